// Round 1
// baseline (2558.608 us; speedup 1.0000x reference)
//
#include <hip/hip_runtime.h>
#include <cstddef>

#define EPSV 1e-5f

// ---------------------------------------------------------------- utilities
__device__ __forceinline__ float wsum(float v) {
  v += __shfl_xor(v, 32, 64);
  v += __shfl_xor(v, 16, 64);
  v += __shfl_xor(v, 8, 64);
  v += __shfl_xor(v, 4, 64);
  v += __shfl_xor(v, 2, 64);
  v += __shfl_xor(v, 1, 64);
  return v;
}

// ---------------------------------------------------------------- embed gather
__global__ __launch_bounds__(128) void k_embed(const int* __restrict__ x,
                                               const float* __restrict__ emb,
                                               float* __restrict__ out) {
  int t = blockIdx.x, tid = threadIdx.x;
  int row = x[t];
  const float4 v = *reinterpret_cast<const float4*>(emb + (size_t)row * 512 + tid * 4);
  *reinterpret_cast<float4*>(out + (size_t)t * 512 + tid * 4) = v;
}

// ---------------------------------------------------------------- layernorm over 512
__global__ __launch_bounds__(128) void k_ln512(const float* __restrict__ in,
                                               const float* __restrict__ w,
                                               float* __restrict__ out) {
  int t = blockIdx.x, tid = threadIdx.x;
  const float4 v = *reinterpret_cast<const float4*>(in + (size_t)t * 512 + tid * 4);
  float s = v.x + v.y + v.z + v.w;
  float s2 = v.x * v.x + v.y * v.y + v.z * v.z + v.w * v.w;
  s = wsum(s); s2 = wsum(s2);
  __shared__ float l1[2], l2[2];
  int wv = tid >> 6;
  if ((tid & 63) == 0) { l1[wv] = s; l2[wv] = s2; }
  __syncthreads();
  s = l1[0] + l1[1]; s2 = l2[0] + l2[1];
  float mu = s * (1.f / 512.f);
  float var = s2 * (1.f / 512.f) - mu * mu;
  float r = rsqrtf(var + EPSV);
  const float4 w4 = *reinterpret_cast<const float4*>(w + tid * 4);
  float4 o;
  o.x = (v.x - mu) * r * w4.x;
  o.y = (v.y - mu) * r * w4.y;
  o.z = (v.z - mu) * r * w4.z;
  o.w = (v.w - mu) * r * w4.w;
  *reinterpret_cast<float4*>(out + (size_t)t * 512 + tid * 4) = o;
}

// ---------------------------------------------------------------- generic batched fp32 GEMM
// C[M,N] = A[M,K] @ B  (+Res).  BT=false: B is [K,N] row-major; BT=true: B is [N,K] row-major.
// Batch offsets: off = (z/HB)*s1 + (z%HB)*s2 for each of A,B,Res,C.
// Requires M%64==0, N%64==0, K%16==0; all pointers/lds 16B-aligned in the fp32 sense.
template <bool BT>
__global__ __launch_bounds__(256) void k_gemm(
    const float* __restrict__ A, size_t sA1, size_t sA2, int lda,
    const float* __restrict__ B, size_t sB1, size_t sB2, int ldb,
    const float* __restrict__ Res, size_t sR1, size_t sR2, int ldr,
    float* __restrict__ C, size_t sC1, size_t sC2, int ldc,
    int M, int N, int K, int HB) {
  const int z = blockIdx.z;
  const int zh = z / HB, zl = z - zh * HB;
  A += zh * sA1 + zl * sA2;
  B += zh * sB1 + zl * sB2;
  C += zh * sC1 + zl * sC2;
  if (Res != nullptr) Res += zh * sR1 + zl * sR2;
  const int bm = blockIdx.y * 64, bn = blockIdx.x * 64;
  const int tid = threadIdx.x;
  const int tx = tid & 15, ty = tid >> 4;
  __shared__ float As[16][68];
  __shared__ float Bs[16][68];
  float acc[4][4] = {{0.f}};
  const int ar = tid >> 2;         // 0..63
  const int akc = (tid & 3) * 4;   // 0,4,8,12
  const int bkr = tid >> 4;        // 0..15
  const int bnc = (tid & 15) * 4;  // 0..60

  for (int k0 = 0; k0 < K; k0 += 16) {
    const float4 av = *reinterpret_cast<const float4*>(A + (size_t)(bm + ar) * lda + (k0 + akc));
    float4 bv;
    if (BT) bv = *reinterpret_cast<const float4*>(B + (size_t)(bn + ar) * ldb + (k0 + akc));
    else    bv = *reinterpret_cast<const float4*>(B + (size_t)(k0 + bkr) * ldb + (bn + bnc));
    As[akc + 0][ar] = av.x; As[akc + 1][ar] = av.y; As[akc + 2][ar] = av.z; As[akc + 3][ar] = av.w;
    if (BT) {
      Bs[akc + 0][ar] = bv.x; Bs[akc + 1][ar] = bv.y; Bs[akc + 2][ar] = bv.z; Bs[akc + 3][ar] = bv.w;
    } else {
      *reinterpret_cast<float4*>(&Bs[bkr][bnc]) = bv;
    }
    __syncthreads();
#pragma unroll
    for (int kk = 0; kk < 16; ++kk) {
      const float4 a4 = *reinterpret_cast<const float4*>(&As[kk][ty * 4]);
      const float4 b4 = *reinterpret_cast<const float4*>(&Bs[kk][tx * 4]);
      const float aa[4] = {a4.x, a4.y, a4.z, a4.w};
      const float bb[4] = {b4.x, b4.y, b4.z, b4.w};
#pragma unroll
      for (int i = 0; i < 4; ++i)
#pragma unroll
        for (int j = 0; j < 4; ++j) acc[i][j] = fmaf(aa[i], bb[j], acc[i][j]);
    }
    __syncthreads();
  }
#pragma unroll
  for (int i = 0; i < 4; ++i) {
    const int r = bm + ty * 4 + i;
    float4 o = make_float4(acc[i][0], acc[i][1], acc[i][2], acc[i][3]);
    if (Res != nullptr) {
      const float4 rv = *reinterpret_cast<const float4*>(Res + (size_t)r * ldr + (bn + tx * 4));
      o.x += rv.x; o.y += rv.y; o.z += rv.z; o.w += rv.w;
    }
    *reinterpret_cast<float4*>(C + (size_t)r * ldc + (bn + tx * 4)) = o;
  }
}

// ---------------------------------------------------------------- causal depthwise conv(K=3)+silu
__global__ __launch_bounds__(256) void k_conv_silu(const float* __restrict__ in, int inLd, int logC,
                                                   const float* __restrict__ w,
                                                   const float* __restrict__ bias,
                                                   float* __restrict__ out) {
  int idx = blockIdx.x * 256 + threadIdx.x;
  int C = 1 << logC;
  int t = idx >> logC, c = idx & (C - 1);
  int s = t & 1023;
  const float* ip = in + (size_t)t * inLd + c;
  float acc = bias[c] + w[c * 3 + 2] * ip[0];
  if (s >= 1) acc += w[c * 3 + 1] * ip[-(ptrdiff_t)inLd];
  if (s >= 2) acc += w[c * 3 + 0] * ip[-2 * (ptrdiff_t)inLd];
  out[(size_t)t * C + c] = acc / (1.f + __expf(-acc));
}

// ---------------------------------------------------------------- block-diagonal q,k,v (4x4 blocks)
__global__ __launch_bounds__(256) void k_qkv(const float* __restrict__ xc, const float* __restrict__ x2,
                                             const float* __restrict__ Wq, const float* __restrict__ Wk,
                                             const float* __restrict__ Wv,
                                             float* __restrict__ q, float* __restrict__ k,
                                             float* __restrict__ v) {
  int t = blockIdx.x, n = threadIdx.x;
  const float4 xcv = *reinterpret_cast<const float4*>(xc + (size_t)t * 1024 + n * 4);
  const float4 xmv = *reinterpret_cast<const float4*>(x2 + (size_t)t * 2048 + n * 4);
  float qa[4], ka[4], va[4];
#pragma unroll
  for (int o = 0; o < 4; ++o) {
    const float4 wq = *reinterpret_cast<const float4*>(Wq + n * 16 + o * 4);
    const float4 wk = *reinterpret_cast<const float4*>(Wk + n * 16 + o * 4);
    const float4 wv = *reinterpret_cast<const float4*>(Wv + n * 16 + o * 4);
    qa[o] = xcv.x * wq.x + xcv.y * wq.y + xcv.z * wq.z + xcv.w * wq.w;
    ka[o] = xcv.x * wk.x + xcv.y * wk.y + xcv.z * wk.z + xcv.w * wk.w;
    va[o] = xmv.x * wv.x + xmv.y * wv.y + xmv.z * wv.z + xmv.w * wv.w;
  }
  *reinterpret_cast<float4*>(q + (size_t)t * 1024 + n * 4) = make_float4(qa[0], qa[1], qa[2], qa[3]);
  *reinterpret_cast<float4*>(k + (size_t)t * 1024 + n * 4) = make_float4(ka[0], ka[1], ka[2], ka[3]);
  *reinterpret_cast<float4*>(v + (size_t)t * 1024 + n * 4) = make_float4(va[0], va[1], va[2], va[3]);
}

// ---------------------------------------------------------------- ig/fg = qkv @ Wi/Wf + bias, layout [b*4+h][s]
__global__ __launch_bounds__(256) void k_igfg(const float* __restrict__ q, const float* __restrict__ k,
                                              const float* __restrict__ v,
                                              const float* __restrict__ Wi, const float* __restrict__ bi,
                                              const float* __restrict__ Wf, const float* __restrict__ bf,
                                              float* __restrict__ ig, float* __restrict__ fg) {
  int t = blockIdx.x, tid = threadIdx.x;
  float aI[4] = {0.f, 0.f, 0.f, 0.f}, aF[4] = {0.f, 0.f, 0.f, 0.f};
  for (int c = tid; c < 1024; c += 256) {
    float qv = q[(size_t)t * 1024 + c];
    float kv = k[(size_t)t * 1024 + c];
    float vv = v[(size_t)t * 1024 + c];
    const float4 wiq = *reinterpret_cast<const float4*>(Wi + (size_t)c * 4);
    const float4 wik = *reinterpret_cast<const float4*>(Wi + (size_t)(1024 + c) * 4);
    const float4 wiv = *reinterpret_cast<const float4*>(Wi + (size_t)(2048 + c) * 4);
    const float4 wfq = *reinterpret_cast<const float4*>(Wf + (size_t)c * 4);
    const float4 wfk = *reinterpret_cast<const float4*>(Wf + (size_t)(1024 + c) * 4);
    const float4 wfv = *reinterpret_cast<const float4*>(Wf + (size_t)(2048 + c) * 4);
    aI[0] += qv * wiq.x + kv * wik.x + vv * wiv.x;
    aI[1] += qv * wiq.y + kv * wik.y + vv * wiv.y;
    aI[2] += qv * wiq.z + kv * wik.z + vv * wiv.z;
    aI[3] += qv * wiq.w + kv * wik.w + vv * wiv.w;
    aF[0] += qv * wfq.x + kv * wfk.x + vv * wfv.x;
    aF[1] += qv * wfq.y + kv * wfk.y + vv * wfv.y;
    aF[2] += qv * wfq.z + kv * wfk.z + vv * wfv.z;
    aF[3] += qv * wfq.w + kv * wfk.w + vv * wfv.w;
  }
#pragma unroll
  for (int h = 0; h < 4; ++h) { aI[h] = wsum(aI[h]); aF[h] = wsum(aF[h]); }
  __shared__ float red[2][4][4];  // [which][wave][h]
  int wv = tid >> 6;
  if ((tid & 63) == 0) {
#pragma unroll
    for (int h = 0; h < 4; ++h) { red[0][wv][h] = aI[h]; red[1][wv][h] = aF[h]; }
  }
  __syncthreads();
  if (tid < 8) {
    int which = tid >> 2, h = tid & 3;
    float sum = red[which][0][h] + red[which][1][h] + red[which][2][h] + red[which][3][h];
    int b = t >> 10, s = t & 1023;
    size_t o = (size_t)(b * 4 + h) * 1024 + s;
    if (which == 0) ig[o] = sum + bi[h];
    else            fg[o] = sum + bf[h];
  }
}

// ---------------------------------------------------------------- per-(b,h) gate scans: a, prefix-max M, exp(-maxD)
__global__ __launch_bounds__(1024) void k_gatescan(const float* __restrict__ ig, const float* __restrict__ fg,
                                                   float* __restrict__ a, float* __restrict__ Mx,
                                                   float* __restrict__ emax) {
  int bh = blockIdx.x, s = threadIdx.x;
  size_t o = (size_t)bh * 1024 + s;
  float f = fg[o];
  float lf = (f >= 0.f) ? -log1pf(__expf(-f)) : (f - log1pf(__expf(f)));
  __shared__ float buf[1024];
  float val = lf;
  buf[s] = val;
  __syncthreads();
#pragma unroll
  for (int off = 1; off < 1024; off <<= 1) {
    float add = (s >= off) ? buf[s - off] : 0.f;
    __syncthreads();
    val += add; buf[s] = val;
    __syncthreads();
  }
  float csv = val;            // inclusive cumsum of log-sigmoid(fg)
  float av = ig[o] - csv;     // a[j]
  float mv = av;
  buf[s] = mv;
  __syncthreads();
#pragma unroll
  for (int off = 1; off < 1024; off <<= 1) {
    float other = (s >= off) ? buf[s - off] : -3.4e38f;
    __syncthreads();
    mv = fmaxf(mv, other); buf[s] = mv;
    __syncthreads();
  }
  a[o] = av;
  Mx[o] = mv;
  emax[o] = __expf(-(csv + mv));   // exp(-maxD[i])
}

// ---------------------------------------------------------------- mask+gate-weight+row-normalize score rows
__global__ __launch_bounds__(256) void k_mask(float* __restrict__ P, const float* __restrict__ a,
                                              const float* __restrict__ Mx, const float* __restrict__ emax,
                                              int bhBase) {
  int i = blockIdx.x, z = blockIdx.y, tid = threadIdx.x;
  int bh = bhBase + z;
  float* Prow = P + ((size_t)z * 1024 + i) * 1024;
  const float* ab = a + (size_t)bh * 1024;
  float Mi = Mx[(size_t)bh * 1024 + i];
  float vals[4];
  float rs = 0.f;
#pragma unroll
  for (int jj = 0; jj < 4; ++jj) {
    int j = tid + jj * 256;
    float pv = 0.f;
    if (j <= i) pv = Prow[j] * 0.0625f * __expf(ab[j] - Mi);
    vals[jj] = pv;
    rs += pv;
  }
  rs = wsum(rs);
  __shared__ float red[4];
  if ((tid & 63) == 0) red[tid >> 6] = rs;
  __syncthreads();
  float tot = red[0] + red[1] + red[2] + red[3];
  float norm = fmaxf(fabsf(tot), emax[(size_t)bh * 1024 + i]) + 1e-6f;
  float inv = 1.f / norm;
#pragma unroll
  for (int jj = 0; jj < 4; ++jj) Prow[tid + jj * 256] = vals[jj] * inv;
}

// ---------------------------------------------------------------- mLSTM headnorm (256) + skip + silu(z) combine
__global__ __launch_bounds__(256) void k_hncomb(const float* __restrict__ hattn, const float* __restrict__ xc,
                                                const float* __restrict__ x2, const float* __restrict__ onorm,
                                                const float* __restrict__ skip, float* __restrict__ out) {
  int t = blockIdx.x, tid = threadIdx.x;
  int w = tid >> 6, lane = tid & 63;
  int cbase = w * 256 + lane * 4;
  const float4 v = *reinterpret_cast<const float4*>(hattn + (size_t)t * 1024 + cbase);
  float s = v.x + v.y + v.z + v.w;
  float s2 = v.x * v.x + v.y * v.y + v.z * v.z + v.w * v.w;
  s = wsum(s); s2 = wsum(s2);
  float mu = s * (1.f / 256.f), var = s2 * (1.f / 256.f) - mu * mu;
  float r = rsqrtf(var + EPSV);
  const float4 on4 = *reinterpret_cast<const float4*>(onorm + cbase);
  const float4 sk4 = *reinterpret_cast<const float4*>(skip + cbase);
  const float4 xc4 = *reinterpret_cast<const float4*>(xc + (size_t)t * 1024 + cbase);
  const float4 z4 = *reinterpret_cast<const float4*>(x2 + (size_t)t * 2048 + 1024 + cbase);
  float4 o;
  o.x = ((v.x - mu) * r * on4.x + sk4.x * xc4.x) * (z4.x / (1.f + __expf(-z4.x)));
  o.y = ((v.y - mu) * r * on4.y + sk4.y * xc4.y) * (z4.y / (1.f + __expf(-z4.y)));
  o.z = ((v.z - mu) * r * on4.z + sk4.z * xc4.z) * (z4.z / (1.f + __expf(-z4.z)));
  o.w = ((v.w - mu) * r * on4.w + sk4.w * xc4.w) * (z4.w / (1.f + __expf(-z4.w)));
  *reinterpret_cast<float4*>(out + (size_t)t * 1024 + cbase) = o;
}

// ---------------------------------------------------------------- concat the 4 sLSTM gate weight tensors
__global__ __launch_bounds__(256) void k_wcat(const float* __restrict__ wi, const float* __restrict__ wf,
                                              const float* __restrict__ wz, const float* __restrict__ wo,
                                              float* __restrict__ Wcat) {
  int idx = blockIdx.x * 256 + threadIdx.x;
  int g = idx >> 16, r = idx & 65535;
  const float* s = (g == 0) ? wi : ((g == 1) ? wf : ((g == 2) ? wz : wo));
  Wcat[idx] = s[r];
}

// ---------------------------------------------------------------- sLSTM sequential scan, one block per (b,h)
// Wx layout: [b][s][h*4+g][e] (row = t, stride 2048);  R: [h][d][g][e];  bias: [g][h][e]
// ys out layout: [b][s][h*128+e]
__global__ __launch_bounds__(1024) void k_scan(const float* __restrict__ Wx, const float* __restrict__ R,
                                               const float* __restrict__ bias, float* __restrict__ ys) {
  int bh = blockIdx.x;
  int b = bh >> 2, h = bh & 3;
  int tid = threadIdx.x;
  int dg = tid >> 7, oq = tid & 127;  // dg: 8 groups of 16 d's; oq: 128 quads of outputs o=g*128+e

  float rr[16][4];
  {
    const float* Rp = R + (size_t)h * 65536 + (size_t)(dg * 16) * 512 + oq * 4;
#pragma unroll
    for (int dd = 0; dd < 16; ++dd) {
      const float4 rv = *reinterpret_cast<const float4*>(Rp + (size_t)dd * 512);
      rr[dd][0] = rv.x; rr[dd][1] = rv.y; rr[dd][2] = rv.z; rr[dd][3] = rv.w;
    }
  }
  float bs[4] = {0.f, 0.f, 0.f, 0.f};
  if (dg == 0) {
#pragma unroll
    for (int j = 0; j < 4; ++j) {
      int o = oq * 4 + j;
      bs[j] = bias[(size_t)(o >> 7) * 512 + h * 128 + (o & 127)];
    }
  }
  const float* wxp = Wx + (size_t)b * 1024 * 2048 + (size_t)h * 512 + oq * 4;

  __shared__ float ysh[128];
  __shared__ float part[8][512];
  float c_ = 0.f, n_ = 0.f, m_ = 0.f;
  if (tid < 128) ysh[tid] = 0.f;
  float4 wxc = make_float4(0.f, 0.f, 0.f, 0.f);
  if (dg == 0) wxc = *reinterpret_cast<const float4*>(wxp);
  __syncthreads();

  for (int s = 0; s < 1024; ++s) {
    float4 wxn = wxc;
    if (dg == 0 && s < 1023) wxn = *reinterpret_cast<const float4*>(wxp + (size_t)(s + 1) * 2048);
    float acc[4];
    if (dg == 0) { acc[0] = wxc.x + bs[0]; acc[1] = wxc.y + bs[1]; acc[2] = wxc.z + bs[2]; acc[3] = wxc.w + bs[3]; }
    else         { acc[0] = 0.f; acc[1] = 0.f; acc[2] = 0.f; acc[3] = 0.f; }
    const float* yp = ysh + dg * 16;
#pragma unroll
    for (int c4 = 0; c4 < 4; ++c4) {
      const float4 yv = *reinterpret_cast<const float4*>(yp + c4 * 4);
#pragma unroll
      for (int j = 0; j < 4; ++j) {
        acc[j] = fmaf(yv.x, rr[c4 * 4 + 0][j], acc[j]);
        acc[j] = fmaf(yv.y, rr[c4 * 4 + 1][j], acc[j]);
        acc[j] = fmaf(yv.z, rr[c4 * 4 + 2][j], acc[j]);
        acc[j] = fmaf(yv.w, rr[c4 * 4 + 3][j], acc[j]);
      }
    }
    *reinterpret_cast<float4*>(&part[dg][oq * 4]) = make_float4(acc[0], acc[1], acc[2], acc[3]);
    __syncthreads();
    if (tid < 128) {
      float4 r0 = *reinterpret_cast<const float4*>(&part[0][tid * 4]);
#pragma unroll
      for (int g2 = 1; g2 < 8; ++g2) {
        const float4 rg = *reinterpret_cast<const float4*>(&part[g2][tid * 4]);
        r0.x += rg.x; r0.y += rg.y; r0.z += rg.z; r0.w += rg.w;
      }
      *reinterpret_cast<float4*>(&part[0][tid * 4]) = r0;
    }
    __syncthreads();
    if (tid < 128) {
      int e = tid;
      float ir = part[0][e];
      float fr = part[0][128 + e];
      float zr = part[0][256 + e];
      float orr = part[0][384 + e];
      float lsf = (fr >= 0.f) ? -log1pf(__expf(-fr)) : (fr - log1pf(__expf(fr)));
      float lfm = m_ + lsf;
      float mn = fmaxf(ir, lfm);
      float igt = __expf(ir - mn);
      float fgt = __expf(lfm - mn);
      float cn = fgt * c_ + igt * tanhf(zr);
      float nn = fgt * n_ + igt;
      float yn = (1.f / (1.f + __expf(-orr))) * cn / nn;
      c_ = cn; n_ = nn; m_ = mn;
      ysh[e] = yn;
      ys[((size_t)b * 1024 + s) * 512 + h * 128 + e] = yn;
    }
    wxc = wxn;
    __syncthreads();
  }
}

// ---------------------------------------------------------------- sLSTM headnorm(128)+gn + residual
__global__ __launch_bounds__(512) void k_hnadd(const float* __restrict__ hin, const float* __restrict__ ysv,
                                               const float* __restrict__ gn, float* __restrict__ out) {
  int t = blockIdx.x, tid = threadIdx.x;
  float yv = ysv[(size_t)t * 512 + tid];
  float s = wsum(yv), s2 = wsum(yv * yv);
  __shared__ float l1[8], l2[8];
  int wv = tid >> 6;
  if ((tid & 63) == 0) { l1[wv] = s; l2[wv] = s2; }
  __syncthreads();
  int h2 = (tid >> 7) * 2;
  float S = l1[h2] + l1[h2 + 1], S2 = l2[h2] + l2[h2 + 1];
  float mu = S * (1.f / 128.f), var = S2 * (1.f / 128.f) - mu * mu;
  float r = rsqrtf(var + EPSV);
  out[(size_t)t * 512 + tid] = hin[(size_t)t * 512 + tid] + (yv - mu) * r * gn[tid];
}

// ---------------------------------------------------------------- gelu(g)*up
__global__ __launch_bounds__(256) void k_geluprod(const float* __restrict__ u, float* __restrict__ gp) {
  int idx = blockIdx.x * 256 + threadIdx.x;
  int t = idx >> 9, c = idx & 511;
  float g = u[(size_t)t * 1024 + c];
  float up = u[(size_t)t * 1024 + 512 + c];
  float ge = 0.5f * g * (1.f + erff(g * 0.70710678118654752f));
  gp[idx] = ge * up;
}

// ---------------------------------------------------------------- final LN(last token) + classifier
__global__ __launch_bounds__(128) void k_final(const float* __restrict__ h, const float* __restrict__ w,
                                               const float* __restrict__ cw, const float* __restrict__ cb,
                                               float* __restrict__ out) {
  int b = blockIdx.x, tid = threadIdx.x;
  const float* row = h + ((size_t)(b * 1024 + 1023)) * 512;
  const float4 v = *reinterpret_cast<const float4*>(row + tid * 4);
  float s = v.x + v.y + v.z + v.w;
  float s2 = v.x * v.x + v.y * v.y + v.z * v.z + v.w * v.w;
  s = wsum(s); s2 = wsum(s2);
  __shared__ float l1[2], l2[2];
  int wv = tid >> 6;
  if ((tid & 63) == 0) { l1[wv] = s; l2[wv] = s2; }
  __syncthreads();
  s = l1[0] + l1[1]; s2 = l2[0] + l2[1];
  float mu = s * (1.f / 512.f);
  float var = s2 * (1.f / 512.f) - mu * mu;
  float r = rsqrtf(var + EPSV);
  const float4 w4 = *reinterpret_cast<const float4*>(w + tid * 4);
  const float4 c4 = *reinterpret_cast<const float4*>(cw + tid * 4);
  float d = (v.x - mu) * r * w4.x * c4.x + (v.y - mu) * r * w4.y * c4.y +
            (v.z - mu) * r * w4.z * c4.z + (v.w - mu) * r * w4.w * c4.w;
  d = wsum(d);
  __syncthreads();
  if ((tid & 63) == 0) l1[tid >> 6] = d;
  __syncthreads();
  if (tid == 0) out[b] = l1[0] + l1[1] + cb[0];
}

// ================================================================ host
extern "C" void kernel_launch(void* const* d_in, const int* in_sizes, int n_in,
                              void* d_out, int out_size, void* d_ws, size_t ws_size,
                              hipStream_t stream) {
  (void)in_sizes; (void)n_in; (void)out_size; (void)ws_size;
  auto F = [&](int i) { return (const float*)d_in[i]; };
  const int* x = (const int*)d_in[0];
  const float* emb = F(1);

  float* ws = (float*)d_ws;
  size_t off = 0;
  auto alloc = [&](size_t n) { float* p = ws + off; off += n; return p; };
  const size_t T = 4096;
  float* hA = alloc(T * 512);
  float* hB = alloc(T * 512);
  float* X2 = alloc(T * 2048);
  float* C1 = alloc(T * 1024);
  float* C2 = alloc(T * 1024);
  float* C3 = alloc(T * 1024);
  float* C4 = alloc(T * 1024);
  float* C5 = alloc(T * 1024);
  float* Pbuf = alloc((size_t)8 * 1024 * 1024);
  float* g_a = alloc(16 * 1024);
  float* g_M = alloc(16 * 1024);
  float* g_e = alloc(16 * 1024);
  float* g_ig = alloc(16 * 1024);
  float* g_fg = alloc(16 * 1024);
  float* Wcat = alloc((size_t)4 * 4 * 128 * 128);

  auto gemm = [&](bool bt, const float* A, size_t sA1, size_t sA2, int lda,
                  const float* Bm, size_t sB1, size_t sB2, int ldb,
                  const float* Res, size_t sR1, size_t sR2, int ldr,
                  float* Cm, size_t sC1, size_t sC2, int ldc,
                  int M, int N, int K, int batch, int HB) {
    dim3 g(N / 64, M / 64, batch), blk(256);
    if (bt)
      k_gemm<true><<<g, blk, 0, stream>>>(A, sA1, sA2, lda, Bm, sB1, sB2, ldb,
                                          Res, sR1, sR2, ldr, Cm, sC1, sC2, ldc, M, N, K, HB);
    else
      k_gemm<false><<<g, blk, 0, stream>>>(A, sA1, sA2, lda, Bm, sB1, sB2, ldb,
                                           Res, sR1, sR2, ldr, Cm, sC1, sC2, ldc, M, N, K, HB);
  };

  // ---------------- embed
  k_embed<<<4096, 128, 0, stream>>>(x, emb, hA);

  // ---------------- mLSTM block
  auto mlstm = [&](int pi, const float* hin, float* hout) {
    const float* ln = F(pi + 0);  const float* Wup = F(pi + 1);
    const float* convW = F(pi + 2); const float* convb = F(pi + 3);
    const float* Wq = F(pi + 4);  const float* Wk = F(pi + 5);  const float* Wv = F(pi + 6);
    const float* Wi = F(pi + 7);  const float* bi = F(pi + 8);
    const float* Wf = F(pi + 9);  const float* bf = F(pi + 10);
    const float* skip = F(pi + 11); const float* onorm = F(pi + 12);
    const float* Wdown = F(pi + 13);

    k_ln512<<<4096, 128, 0, stream>>>(hin, ln, C2);
    gemm(false, C2, 0, 0, 512, Wup, 0, 0, 2048, nullptr, 0, 0, 0, X2, 0, 0, 2048,
         4096, 2048, 512, 1, 1);
    k_conv_silu<<<(4096 * 1024) / 256, 256, 0, stream>>>(X2, 2048, 10, convW, convb, C1);
    k_qkv<<<4096, 256, 0, stream>>>(C1, X2, Wq, Wk, Wv, C2, C3, C4);
    k_igfg<<<4096, 256, 0, stream>>>(C2, C3, C4, Wi, bi, Wf, bf, g_ig, g_fg);
    k_gatescan<<<16, 1024, 0, stream>>>(g_ig, g_fg, g_a, g_M, g_e);

    for (int chunk = 0; chunk < 2; ++chunk) {
      size_t co = (size_t)chunk * 2 * 1024 * 1024;  // 2 batches worth of (S*1024) floats
      // scores = q @ k^T   (per bh: M=N=1024, K=256)
      gemm(true, C2 + co, (size_t)1024 * 1024, 256, 1024,
                 C3 + co, (size_t)1024 * 1024, 256, 1024,
                 nullptr, 0, 0, 0,
                 Pbuf, (size_t)4 * 1024 * 1024, (size_t)1024 * 1024, 1024,
                 1024, 1024, 256, 8, 4);
      k_mask<<<dim3(1024, 8), 256, 0, stream>>>(Pbuf, g_a, g_M, g_e, chunk * 8);
      // hattn = P @ v      (per bh: M=1024, N=256, K=1024)
      gemm(false, Pbuf, (size_t)4 * 1024 * 1024, (size_t)1024 * 1024, 1024,
                  C4 + co, (size_t)1024 * 1024, 256, 1024,
                  nullptr, 0, 0, 0,
                  C5 + co, (size_t)1024 * 1024, 256, 1024,
                  1024, 256, 1024, 8, 4);
    }
    k_hncomb<<<4096, 256, 0, stream>>>(C5, C1, X2, onorm, skip, C2);
    gemm(false, C2, 0, 0, 1024, Wdown, 0, 0, 512, hin, 0, 0, 512, hout, 0, 0, 512,
         4096, 512, 1024, 1, 1);
  };

  // ---------------- sLSTM block
  auto slstm = [&](const float* hin, float* hout) {
    const float* ln1 = F(30); const float* convW = F(31); const float* convb = F(32);
    const float* Wig = F(33); const float* Wfg = F(34); const float* Wzg = F(35);
    const float* Wog = F(36); const float* Rr = F(37);  const float* bias = F(38);
    const float* gn = F(39);  const float* ln2 = F(40);
    const float* Wu = F(41);  const float* Wd = F(42);

    k_ln512<<<4096, 128, 0, stream>>>(hin, ln1, C3);                       // xn
    k_conv_silu<<<(4096 * 512) / 256, 256, 0, stream>>>(C3, 512, 9, convW, convb, C4);  // xc
    k_wcat<<<(4 * 65536) / 256, 256, 0, stream>>>(Wig, Wfg, Wzg, Wog, Wcat);
    // gates i,f from xc  (batch z=h*2+g, HB=2)
    gemm(true, C4, 128, 0, 512, Wcat, 16384, 65536, 128, nullptr, 0, 0, 0,
         X2, 512, 128, 2048, 4096, 128, 128, 8, 2);
    // gates z,o from xn
    gemm(true, C3, 128, 0, 512, Wcat + (size_t)2 * 65536, 16384, 65536, 128, nullptr, 0, 0, 0,
         X2 + 256, 512, 128, 2048, 4096, 128, 128, 8, 2);
    k_scan<<<16, 1024, 0, stream>>>(X2, Rr, bias, C2);                      // ys
    k_hnadd<<<4096, 512, 0, stream>>>(hin, C2, gn, C3);                     // hmid
    k_ln512<<<4096, 128, 0, stream>>>(C3, ln2, C4);
    gemm(false, C4, 0, 0, 512, Wu, 0, 0, 1024, nullptr, 0, 0, 0, C5, 0, 0, 1024,
         4096, 1024, 512, 1, 1);
    k_geluprod<<<(4096 * 512) / 256, 256, 0, stream>>>(C5, C1);
    gemm(false, C1, 0, 0, 512, Wd, 0, 0, 512, C3, 0, 0, 512, hout, 0, 0, 512,
         4096, 512, 512, 1, 1);
  };

  mlstm(2, hA, hB);
  slstm(hB, hA);
  mlstm(16, hA, hB);
  k_final<<<4, 128, 0, stream>>>(hB, F(43), F(44), F(45), (float*)d_out);
}

// Round 2
// 2073.870 us; speedup vs baseline: 1.2337x; 1.2337x over previous
//
#include <hip/hip_runtime.h>
#include <cstddef>
#include <cstdint>

#define EPSV 1e-5f

typedef __attribute__((ext_vector_type(8))) short bf16x8;  // 8 bf16 = 4 VGPRs
typedef __attribute__((ext_vector_type(4))) float f32x4;

__device__ __forceinline__ short f2bf(float f) {
  union { float f; unsigned u; } v; v.f = f;
  unsigned r = (v.u + 0x7FFFu + ((v.u >> 16) & 1u)) >> 16;  // RNE
  return (short)r;
}
__device__ __forceinline__ float bf2f(short s) {
  union { unsigned u; float f; } v; v.u = ((unsigned)(unsigned short)s) << 16;
  return v.f;
}

__device__ __forceinline__ float wsum(float v) {
  v += __shfl_xor(v, 32, 64);
  v += __shfl_xor(v, 16, 64);
  v += __shfl_xor(v, 8, 64);
  v += __shfl_xor(v, 4, 64);
  v += __shfl_xor(v, 2, 64);
  v += __shfl_xor(v, 1, 64);
  return v;
}

// ---------------------------------------------------------------- embed gather
__global__ __launch_bounds__(128) void k_embed(const int* __restrict__ x,
                                               const float* __restrict__ emb,
                                               float* __restrict__ out) {
  int t = blockIdx.x, tid = threadIdx.x;
  int row = x[t];
  const float4 v = *reinterpret_cast<const float4*>(emb + (size_t)row * 512 + tid * 4);
  *reinterpret_cast<float4*>(out + (size_t)t * 512 + tid * 4) = v;
}

// ---------------------------------------------------------------- layernorm over 512 (fp32 optional + bf16 out)
__global__ __launch_bounds__(128) void k_ln512(const float* __restrict__ in,
                                               const float* __restrict__ w,
                                               float* __restrict__ outf,
                                               short* __restrict__ out16) {
  int t = blockIdx.x, tid = threadIdx.x;
  const float4 v = *reinterpret_cast<const float4*>(in + (size_t)t * 512 + tid * 4);
  float s = v.x + v.y + v.z + v.w;
  float s2 = v.x * v.x + v.y * v.y + v.z * v.z + v.w * v.w;
  s = wsum(s); s2 = wsum(s2);
  __shared__ float l1[2], l2[2];
  int wv = tid >> 6;
  if ((tid & 63) == 0) { l1[wv] = s; l2[wv] = s2; }
  __syncthreads();
  s = l1[0] + l1[1]; s2 = l2[0] + l2[1];
  float mu = s * (1.f / 512.f);
  float var = s2 * (1.f / 512.f) - mu * mu;
  float r = rsqrtf(var + EPSV);
  const float4 w4 = *reinterpret_cast<const float4*>(w + tid * 4);
  float4 o;
  o.x = (v.x - mu) * r * w4.x;
  o.y = (v.y - mu) * r * w4.y;
  o.z = (v.z - mu) * r * w4.z;
  o.w = (v.w - mu) * r * w4.w;
  if (outf) *reinterpret_cast<float4*>(outf + (size_t)t * 512 + tid * 4) = o;
  *reinterpret_cast<short4*>(out16 + (size_t)t * 512 + tid * 4) =
      make_short4(f2bf(o.x), f2bf(o.y), f2bf(o.z), f2bf(o.w));
}

// ---------------------------------------------------------------- bf16 MFMA GEMM, 128x128 tile, BK=64
// C[M,N] = A[M,K] @ B^T  where both A and B are stored [rows][K] row-major bf16.
// Batch offsets: off = (z/HB)*s1 + (z%HB)*s2 (elements). OUT16: write bf16; else fp32 (+Res).
template <bool OUT16, bool RES>
__global__ __launch_bounds__(256) void k_mm(
    const short* __restrict__ A, size_t sA1, size_t sA2, int lda,
    const short* __restrict__ B, size_t sB1, size_t sB2, int ldb,
    const float* __restrict__ Res, size_t sR1, size_t sR2, int ldr,
    void* __restrict__ Cv, size_t sC1, size_t sC2, int ldc,
    int K, int HB) {
  const int z = blockIdx.z, zh = z / HB, zl = z - zh * HB;
  A += zh * sA1 + zl * sA2;
  B += zh * sB1 + zl * sB2;
  const int bm = blockIdx.y * 128, bn = blockIdx.x * 128;
  const int tid = threadIdx.x, lane = tid & 63, w = tid >> 6;
  const int wr = w >> 1, wc = w & 1;
  const int l15 = lane & 15, l4 = lane >> 4;
  __shared__ short As[128 * 72];  // row stride 72 shorts = 144B (bank-friendly)
  __shared__ short Bs[128 * 72];
  f32x4 acc[4][4];
#pragma unroll
  for (int i = 0; i < 4; ++i)
#pragma unroll
    for (int j = 0; j < 4; ++j) acc[i][j] = (f32x4){0.f, 0.f, 0.f, 0.f};
  const int srow = tid >> 3, sg = tid & 7;
  for (int k0 = 0; k0 < K; k0 += 64) {
    int4 ra[4], rb[4];
#pragma unroll
    for (int it = 0; it < 4; ++it) {
      int row = it * 32 + srow;
      ra[it] = *reinterpret_cast<const int4*>(A + (size_t)(bm + row) * lda + k0 + sg * 8);
      rb[it] = *reinterpret_cast<const int4*>(B + (size_t)(bn + row) * ldb + k0 + sg * 8);
    }
    __syncthreads();  // previous tile fully consumed
#pragma unroll
    for (int it = 0; it < 4; ++it) {
      int row = it * 32 + srow;
      *reinterpret_cast<int4*>(As + row * 72 + sg * 8) = ra[it];
      *reinterpret_cast<int4*>(Bs + row * 72 + sg * 8) = rb[it];
    }
    __syncthreads();
#pragma unroll
    for (int kk = 0; kk < 2; ++kk) {
      bf16x8 af[4], bfr[4];
#pragma unroll
      for (int i = 0; i < 4; ++i) {
        af[i]  = *reinterpret_cast<const bf16x8*>(As + (wr * 64 + i * 16 + l15) * 72 + kk * 32 + l4 * 8);
        bfr[i] = *reinterpret_cast<const bf16x8*>(Bs + (wc * 64 + i * 16 + l15) * 72 + kk * 32 + l4 * 8);
      }
#pragma unroll
      for (int i = 0; i < 4; ++i)
#pragma unroll
        for (int j = 0; j < 4; ++j)
          acc[i][j] = __builtin_amdgcn_mfma_f32_16x16x32_bf16(af[i], bfr[j], acc[i][j], 0, 0, 0);
    }
  }
  // epilogue: C/D layout col=lane&15, row=(lane>>4)*4+r  [m89/m91 verified]
  const int row0 = bm + wr * 64 + l4 * 4, col0 = bn + wc * 64 + l15;
  if constexpr (OUT16) {
    short* C = (short*)Cv + zh * sC1 + zl * sC2;
#pragma unroll
    for (int mi = 0; mi < 4; ++mi)
#pragma unroll
      for (int r = 0; r < 4; ++r) {
        size_t ro = (size_t)(row0 + mi * 16 + r) * ldc;
#pragma unroll
        for (int ni = 0; ni < 4; ++ni) C[ro + col0 + ni * 16] = f2bf(acc[mi][ni][r]);
      }
  } else {
    float* C = (float*)Cv + zh * sC1 + zl * sC2;
    const float* Rp = Res ? (Res + zh * sR1 + zl * sR2) : nullptr;
#pragma unroll
    for (int mi = 0; mi < 4; ++mi)
#pragma unroll
      for (int r = 0; r < 4; ++r) {
        int rw = row0 + mi * 16 + r;
#pragma unroll
        for (int ni = 0; ni < 4; ++ni) {
          float vv = acc[mi][ni][r];
          if constexpr (RES) vv += Rp[(size_t)rw * ldr + col0 + ni * 16];
          C[(size_t)rw * ldc + col0 + ni * 16] = vv;
        }
      }
  }
}

// ---------------------------------------------------------------- transpose-convert fp32[R][C] -> bf16[C][R]
__global__ __launch_bounds__(256) void k_transp(const float* __restrict__ in, size_t sI1, size_t sI2, int ldi,
                                                short* __restrict__ out, size_t sO1, size_t sO2, int ldo,
                                                int HB) {
  __shared__ float t[32][33];
  int z = blockIdx.z, zh = z / HB, zl = z - zh * HB;
  in += zh * sI1 + zl * sI2;
  out += zh * sO1 + zl * sO2;
  int r0 = blockIdx.x * 32, c0 = blockIdx.y * 32;
  int tx = threadIdx.x & 31, ty = threadIdx.x >> 5;
#pragma unroll
  for (int i = 0; i < 4; ++i) {
    int rr = ty + i * 8;
    t[rr][tx] = in[(size_t)(r0 + rr) * ldi + c0 + tx];
  }
  __syncthreads();
#pragma unroll
  for (int i = 0; i < 4; ++i) {
    int cr = ty + i * 8;
    out[(size_t)(c0 + cr) * ldo + r0 + tx] = f2bf(t[tx][cr]);
  }
}

// ---------------------------------------------------------------- causal depthwise conv(K=3)+silu (+bf16 out)
__global__ __launch_bounds__(256) void k_conv_silu(const float* __restrict__ in, int inLd, int logC,
                                                   const float* __restrict__ w,
                                                   const float* __restrict__ bias,
                                                   float* __restrict__ out,
                                                   short* __restrict__ out16) {
  int idx = blockIdx.x * 256 + threadIdx.x;
  int C = 1 << logC;
  int t = idx >> logC, c = idx & (C - 1);
  int s = t & 1023;
  const float* ip = in + (size_t)t * inLd + c;
  float acc = bias[c] + w[c * 3 + 2] * ip[0];
  if (s >= 1) acc += w[c * 3 + 1] * ip[-(ptrdiff_t)inLd];
  if (s >= 2) acc += w[c * 3 + 0] * ip[-2 * (ptrdiff_t)inLd];
  float r = acc / (1.f + __expf(-acc));
  out[(size_t)t * C + c] = r;
  if (out16) out16[(size_t)t * C + c] = f2bf(r);
}

// ---------------------------------------------------------------- block-diagonal q,k,v (4x4 blocks) + bf16 q,k
__global__ __launch_bounds__(256) void k_qkv(const float* __restrict__ xc, const float* __restrict__ x2,
                                             const float* __restrict__ Wq, const float* __restrict__ Wk,
                                             const float* __restrict__ Wv,
                                             float* __restrict__ q, float* __restrict__ k,
                                             float* __restrict__ v,
                                             short* __restrict__ q16, short* __restrict__ k16) {
  int t = blockIdx.x, n = threadIdx.x;
  const float4 xcv = *reinterpret_cast<const float4*>(xc + (size_t)t * 1024 + n * 4);
  const float4 xmv = *reinterpret_cast<const float4*>(x2 + (size_t)t * 2048 + n * 4);
  float qa[4], ka[4], va[4];
#pragma unroll
  for (int o = 0; o < 4; ++o) {
    const float4 wq = *reinterpret_cast<const float4*>(Wq + n * 16 + o * 4);
    const float4 wk = *reinterpret_cast<const float4*>(Wk + n * 16 + o * 4);
    const float4 wv = *reinterpret_cast<const float4*>(Wv + n * 16 + o * 4);
    qa[o] = xcv.x * wq.x + xcv.y * wq.y + xcv.z * wq.z + xcv.w * wq.w;
    ka[o] = xcv.x * wk.x + xcv.y * wk.y + xcv.z * wk.z + xcv.w * wk.w;
    va[o] = xmv.x * wv.x + xmv.y * wv.y + xmv.z * wv.z + xmv.w * wv.w;
  }
  *reinterpret_cast<float4*>(q + (size_t)t * 1024 + n * 4) = make_float4(qa[0], qa[1], qa[2], qa[3]);
  *reinterpret_cast<float4*>(k + (size_t)t * 1024 + n * 4) = make_float4(ka[0], ka[1], ka[2], ka[3]);
  *reinterpret_cast<float4*>(v + (size_t)t * 1024 + n * 4) = make_float4(va[0], va[1], va[2], va[3]);
  *reinterpret_cast<short4*>(q16 + (size_t)t * 1024 + n * 4) =
      make_short4(f2bf(qa[0]), f2bf(qa[1]), f2bf(qa[2]), f2bf(qa[3]));
  *reinterpret_cast<short4*>(k16 + (size_t)t * 1024 + n * 4) =
      make_short4(f2bf(ka[0]), f2bf(ka[1]), f2bf(ka[2]), f2bf(ka[3]));
}

// ---------------------------------------------------------------- ig/fg = qkv @ Wi/Wf + bias, layout [b*4+h][s]
__global__ __launch_bounds__(256) void k_igfg(const float* __restrict__ q, const float* __restrict__ k,
                                              const float* __restrict__ v,
                                              const float* __restrict__ Wi, const float* __restrict__ bi,
                                              const float* __restrict__ Wf, const float* __restrict__ bf,
                                              float* __restrict__ ig, float* __restrict__ fg) {
  int t = blockIdx.x, tid = threadIdx.x;
  float aI[4] = {0.f, 0.f, 0.f, 0.f}, aF[4] = {0.f, 0.f, 0.f, 0.f};
  for (int c = tid; c < 1024; c += 256) {
    float qv = q[(size_t)t * 1024 + c];
    float kv = k[(size_t)t * 1024 + c];
    float vv = v[(size_t)t * 1024 + c];
    const float4 wiq = *reinterpret_cast<const float4*>(Wi + (size_t)c * 4);
    const float4 wik = *reinterpret_cast<const float4*>(Wi + (size_t)(1024 + c) * 4);
    const float4 wiv = *reinterpret_cast<const float4*>(Wi + (size_t)(2048 + c) * 4);
    const float4 wfq = *reinterpret_cast<const float4*>(Wf + (size_t)c * 4);
    const float4 wfk = *reinterpret_cast<const float4*>(Wf + (size_t)(1024 + c) * 4);
    const float4 wfv = *reinterpret_cast<const float4*>(Wf + (size_t)(2048 + c) * 4);
    aI[0] += qv * wiq.x + kv * wik.x + vv * wiv.x;
    aI[1] += qv * wiq.y + kv * wik.y + vv * wiv.y;
    aI[2] += qv * wiq.z + kv * wik.z + vv * wiv.z;
    aI[3] += qv * wiq.w + kv * wik.w + vv * wiv.w;
    aF[0] += qv * wfq.x + kv * wfk.x + vv * wfv.x;
    aF[1] += qv * wfq.y + kv * wfk.y + vv * wfv.y;
    aF[2] += qv * wfq.z + kv * wfk.z + vv * wfv.z;
    aF[3] += qv * wfq.w + kv * wfk.w + vv * wfv.w;
  }
#pragma unroll
  for (int h = 0; h < 4; ++h) { aI[h] = wsum(aI[h]); aF[h] = wsum(aF[h]); }
  __shared__ float red[2][4][4];
  int wv = tid >> 6;
  if ((tid & 63) == 0) {
#pragma unroll
    for (int h = 0; h < 4; ++h) { red[0][wv][h] = aI[h]; red[1][wv][h] = aF[h]; }
  }
  __syncthreads();
  if (tid < 8) {
    int which = tid >> 2, h = tid & 3;
    float sum = red[which][0][h] + red[which][1][h] + red[which][2][h] + red[which][3][h];
    int b = t >> 10, s = t & 1023;
    size_t o = (size_t)(b * 4 + h) * 1024 + s;
    if (which == 0) ig[o] = sum + bi[h];
    else            fg[o] = sum + bf[h];
  }
}

// ---------------------------------------------------------------- per-(b,h) gate scans
__global__ __launch_bounds__(1024) void k_gatescan(const float* __restrict__ ig, const float* __restrict__ fg,
                                                   float* __restrict__ a, float* __restrict__ Mx,
                                                   float* __restrict__ emax) {
  int bh = blockIdx.x, s = threadIdx.x;
  size_t o = (size_t)bh * 1024 + s;
  float f = fg[o];
  float lf = (f >= 0.f) ? -log1pf(__expf(-f)) : (f - log1pf(__expf(f)));
  __shared__ float buf[1024];
  float val = lf;
  buf[s] = val;
  __syncthreads();
#pragma unroll
  for (int off = 1; off < 1024; off <<= 1) {
    float add = (s >= off) ? buf[s - off] : 0.f;
    __syncthreads();
    val += add; buf[s] = val;
    __syncthreads();
  }
  float csv = val;
  float av = ig[o] - csv;
  float mv = av;
  buf[s] = mv;
  __syncthreads();
#pragma unroll
  for (int off = 1; off < 1024; off <<= 1) {
    float other = (s >= off) ? buf[s - off] : -3.4e38f;
    __syncthreads();
    mv = fmaxf(mv, other); buf[s] = mv;
    __syncthreads();
  }
  a[o] = av;
  Mx[o] = mv;
  emax[o] = __expf(-(csv + mv));
}

// ---------------------------------------------------------------- mask+gate-weight+row-normalize (bf16, in place)
__global__ __launch_bounds__(256) void k_mask(short* __restrict__ P, const float* __restrict__ a,
                                              const float* __restrict__ Mx, const float* __restrict__ emax,
                                              int bhBase) {
  int i = blockIdx.x, z = blockIdx.y, tid = threadIdx.x;
  int bh = bhBase + z;
  short* Prow = P + ((size_t)z * 1024 + i) * 1024;
  const float* ab = a + (size_t)bh * 1024;
  float Mi = Mx[(size_t)bh * 1024 + i];
  float vals[4];
  float rs = 0.f;
#pragma unroll
  for (int jj = 0; jj < 4; ++jj) {
    int j = tid + jj * 256;
    float pv = 0.f;
    if (j <= i) pv = bf2f(Prow[j]) * 0.0625f * __expf(ab[j] - Mi);
    vals[jj] = pv;
    rs += pv;
  }
  rs = wsum(rs);
  __shared__ float red[4];
  if ((tid & 63) == 0) red[tid >> 6] = rs;
  __syncthreads();
  float tot = red[0] + red[1] + red[2] + red[3];
  float norm = fmaxf(fabsf(tot), emax[(size_t)bh * 1024 + i]) + 1e-6f;
  float inv = 1.f / norm;
#pragma unroll
  for (int jj = 0; jj < 4; ++jj) Prow[tid + jj * 256] = f2bf(vals[jj] * inv);
}

// ---------------------------------------------------------------- mLSTM headnorm + skip + silu(z) combine -> bf16
__global__ __launch_bounds__(256) void k_hncomb(const float* __restrict__ hattn, const float* __restrict__ xc,
                                                const float* __restrict__ x2, const float* __restrict__ onorm,
                                                const float* __restrict__ skip, short* __restrict__ out) {
  int t = blockIdx.x, tid = threadIdx.x;
  int w = tid >> 6, lane = tid & 63;
  int cbase = w * 256 + lane * 4;
  const float4 v = *reinterpret_cast<const float4*>(hattn + (size_t)t * 1024 + cbase);
  float s = v.x + v.y + v.z + v.w;
  float s2 = v.x * v.x + v.y * v.y + v.z * v.z + v.w * v.w;
  s = wsum(s); s2 = wsum(s2);
  float mu = s * (1.f / 256.f), var = s2 * (1.f / 256.f) - mu * mu;
  float r = rsqrtf(var + EPSV);
  const float4 on4 = *reinterpret_cast<const float4*>(onorm + cbase);
  const float4 sk4 = *reinterpret_cast<const float4*>(skip + cbase);
  const float4 xc4 = *reinterpret_cast<const float4*>(xc + (size_t)t * 1024 + cbase);
  const float4 z4 = *reinterpret_cast<const float4*>(x2 + (size_t)t * 2048 + 1024 + cbase);
  float4 o;
  o.x = ((v.x - mu) * r * on4.x + sk4.x * xc4.x) * (z4.x / (1.f + __expf(-z4.x)));
  o.y = ((v.y - mu) * r * on4.y + sk4.y * xc4.y) * (z4.y / (1.f + __expf(-z4.y)));
  o.z = ((v.z - mu) * r * on4.z + sk4.z * xc4.z) * (z4.z / (1.f + __expf(-z4.z)));
  o.w = ((v.w - mu) * r * on4.w + sk4.w * xc4.w) * (z4.w / (1.f + __expf(-z4.w)));
  *reinterpret_cast<short4*>(out + (size_t)t * 1024 + cbase) =
      make_short4(f2bf(o.x), f2bf(o.y), f2bf(o.z), f2bf(o.w));
}

// ---------------------------------------------------------------- concat+convert sLSTM gate weights -> bf16
__global__ __launch_bounds__(256) void k_wcat(const float* __restrict__ wi, const float* __restrict__ wf,
                                              const float* __restrict__ wz, const float* __restrict__ wo,
                                              short* __restrict__ Wcat) {
  int idx = blockIdx.x * 256 + threadIdx.x;
  int g = idx >> 16, r = idx & 65535;
  const float* s = (g == 0) ? wi : ((g == 1) ? wf : ((g == 2) ? wz : wo));
  Wcat[idx] = f2bf(s[r]);
}

// ---------------------------------------------------------------- sLSTM sequential scan, one block per (b,h)
// 512 threads = 4 d-groups x 128 output-quads; R held in 128 VGPRs/thread; 2 barriers/step.
__global__ __launch_bounds__(512, 2) void k_scan(const float* __restrict__ Wx, const float* __restrict__ R,
                                                 const float* __restrict__ bias, float* __restrict__ ys) {
  int bh = blockIdx.x, b = bh >> 2, h = bh & 3;
  int tid = threadIdx.x;
  int dg = tid >> 7, oq = tid & 127;
  float rr[32][4];  // R[h][dg*32+d2][oq*4+j]
  {
    const float* Rp = R + (size_t)h * 65536 + (size_t)(dg * 32) * 512 + oq * 4;
#pragma unroll
    for (int d2 = 0; d2 < 32; ++d2) {
      const float4 rv = *reinterpret_cast<const float4*>(Rp + (size_t)d2 * 512);
      rr[d2][0] = rv.x; rr[d2][1] = rv.y; rr[d2][2] = rv.z; rr[d2][3] = rv.w;
    }
  }
  __shared__ float ysh[128];
  __shared__ float part[4][512];
  float c_ = 0.f, n_ = 0.f, m_ = 0.f;
  float bsv[4] = {0.f, 0.f, 0.f, 0.f}, wx[4] = {0.f, 0.f, 0.f, 0.f};
  const float* wxp = Wx;
  if (tid < 128) {
    int e = tid;
#pragma unroll
    for (int g = 0; g < 4; ++g) bsv[g] = bias[(size_t)g * 512 + h * 128 + e];
    wxp = Wx + (size_t)b * 1024 * 2048 + h * 512 + e;
#pragma unroll
    for (int g = 0; g < 4; ++g) wx[g] = wxp[g * 128];
    ysh[e] = 0.f;
  }
  __syncthreads();
  for (int s = 0; s < 1024; ++s) {
    float a0 = 0.f, a1 = 0.f, a2 = 0.f, a3 = 0.f;
    const float* yp = ysh + dg * 32;
#pragma unroll
    for (int c4 = 0; c4 < 8; ++c4) {
      const float4 yv = *reinterpret_cast<const float4*>(yp + c4 * 4);
      a0 = fmaf(yv.x, rr[c4 * 4 + 0][0], a0); a1 = fmaf(yv.x, rr[c4 * 4 + 0][1], a1);
      a2 = fmaf(yv.x, rr[c4 * 4 + 0][2], a2); a3 = fmaf(yv.x, rr[c4 * 4 + 0][3], a3);
      a0 = fmaf(yv.y, rr[c4 * 4 + 1][0], a0); a1 = fmaf(yv.y, rr[c4 * 4 + 1][1], a1);
      a2 = fmaf(yv.y, rr[c4 * 4 + 1][2], a2); a3 = fmaf(yv.y, rr[c4 * 4 + 1][3], a3);
      a0 = fmaf(yv.z, rr[c4 * 4 + 2][0], a0); a1 = fmaf(yv.z, rr[c4 * 4 + 2][1], a1);
      a2 = fmaf(yv.z, rr[c4 * 4 + 2][2], a2); a3 = fmaf(yv.z, rr[c4 * 4 + 2][3], a3);
      a0 = fmaf(yv.w, rr[c4 * 4 + 3][0], a0); a1 = fmaf(yv.w, rr[c4 * 4 + 3][1], a1);
      a2 = fmaf(yv.w, rr[c4 * 4 + 3][2], a2); a3 = fmaf(yv.w, rr[c4 * 4 + 3][3], a3);
    }
    *reinterpret_cast<float4*>(&part[dg][oq * 4]) = make_float4(a0, a1, a2, a3);
    __syncthreads();
    if (tid < 128) {
      int e = tid;
      float raw[4];
#pragma unroll
      for (int g = 0; g < 4; ++g)
        raw[g] = wx[g] + bsv[g] +
                 ((part[0][g * 128 + e] + part[1][g * 128 + e]) +
                  (part[2][g * 128 + e] + part[3][g * 128 + e]));
      int sp = (s + 1 < 1024) ? (s + 1) : 1023;  // prefetch next wx
#pragma unroll
      for (int g = 0; g < 4; ++g) wx[g] = wxp[(size_t)sp * 2048 + g * 128];
      float fr = raw[1];
      float lsf = (fr >= 0.f) ? -log1pf(__expf(-fr)) : (fr - log1pf(__expf(fr)));
      float lfm = m_ + lsf;
      float mn = fmaxf(raw[0], lfm);
      float igt = __expf(raw[0] - mn);
      float fgt = __expf(lfm - mn);
      float cn = fgt * c_ + igt * tanhf(raw[2]);
      float nn = fgt * n_ + igt;
      float yn = (1.f / (1.f + __expf(-raw[3]))) * cn / nn;
      c_ = cn; n_ = nn; m_ = mn;
      ysh[e] = yn;
      ys[((size_t)b * 1024 + s) * 512 + h * 128 + e] = yn;
    }
    __syncthreads();
  }
}

// ---------------------------------------------------------------- sLSTM headnorm(128)+gn + residual
__global__ __launch_bounds__(512) void k_hnadd(const float* __restrict__ hin, const float* __restrict__ ysv,
                                               const float* __restrict__ gn, float* __restrict__ out) {
  int t = blockIdx.x, tid = threadIdx.x;
  float yv = ysv[(size_t)t * 512 + tid];
  float s = wsum(yv), s2 = wsum(yv * yv);
  __shared__ float l1[8], l2[8];
  int wv = tid >> 6;
  if ((tid & 63) == 0) { l1[wv] = s; l2[wv] = s2; }
  __syncthreads();
  int h2 = (tid >> 7) * 2;
  float S = l1[h2] + l1[h2 + 1], S2 = l2[h2] + l2[h2 + 1];
  float mu = S * (1.f / 128.f), var = S2 * (1.f / 128.f) - mu * mu;
  float r = rsqrtf(var + EPSV);
  out[(size_t)t * 512 + tid] = hin[(size_t)t * 512 + tid] + (yv - mu) * r * gn[tid];
}

// ---------------------------------------------------------------- gelu(g)*up -> bf16
__global__ __launch_bounds__(256) void k_geluprod(const float* __restrict__ u, short* __restrict__ gp) {
  int idx = blockIdx.x * 256 + threadIdx.x;
  int t = idx >> 9, c = idx & 511;
  float g = u[(size_t)t * 1024 + c];
  float up = u[(size_t)t * 1024 + 512 + c];
  float ge = 0.5f * g * (1.f + erff(g * 0.70710678118654752f));
  gp[idx] = f2bf(ge * up);
}

// ---------------------------------------------------------------- final LN(last token) + classifier
__global__ __launch_bounds__(128) void k_final(const float* __restrict__ h, const float* __restrict__ w,
                                               const float* __restrict__ cw, const float* __restrict__ cb,
                                               float* __restrict__ out) {
  int b = blockIdx.x, tid = threadIdx.x;
  const float* row = h + ((size_t)(b * 1024 + 1023)) * 512;
  const float4 v = *reinterpret_cast<const float4*>(row + tid * 4);
  float s = v.x + v.y + v.z + v.w;
  float s2 = v.x * v.x + v.y * v.y + v.z * v.z + v.w * v.w;
  s = wsum(s); s2 = wsum(s2);
  __shared__ float l1[2], l2[2];
  int wv = tid >> 6;
  if ((tid & 63) == 0) { l1[wv] = s; l2[wv] = s2; }
  __syncthreads();
  s = l1[0] + l1[1]; s2 = l2[0] + l2[1];
  float mu = s * (1.f / 512.f);
  float var = s2 * (1.f / 512.f) - mu * mu;
  float r = rsqrtf(var + EPSV);
  const float4 w4 = *reinterpret_cast<const float4*>(w + tid * 4);
  const float4 c4 = *reinterpret_cast<const float4*>(cw + tid * 4);
  float d = (v.x - mu) * r * w4.x * c4.x + (v.y - mu) * r * w4.y * c4.y +
            (v.z - mu) * r * w4.z * c4.z + (v.w - mu) * r * w4.w * c4.w;
  d = wsum(d);
  __syncthreads();
  if ((tid & 63) == 0) l1[tid >> 6] = d;
  __syncthreads();
  if (tid == 0) out[b] = l1[0] + l1[1] + cb[0];
}

// ================================================================ host
extern "C" void kernel_launch(void* const* d_in, const int* in_sizes, int n_in,
                              void* d_out, int out_size, void* d_ws, size_t ws_size,
                              hipStream_t stream) {
  (void)in_sizes; (void)n_in; (void)out_size; (void)ws_size;
  auto F = [&](int i) { return (const float*)d_in[i]; };
  const int* x = (const int*)d_in[0];
  const float* emb = F(1);

  float* ws = (float*)d_ws;
  size_t off = 0;
  auto alloc = [&](size_t n) { float* p = ws + off; off += n; return p; };
  float* hA = alloc(2097152);
  float* hB = alloc(2097152);
  float* X2 = alloc(8388608);
  float* C1 = alloc(4194304);
  float* C2 = alloc(4194304);
  float* C3 = alloc(4194304);
  float* C4 = alloc(4194304);
  float* C5 = alloc(4194304);
  float* g_a = alloc(16384);
  float* g_M = alloc(16384);
  float* g_e = alloc(16384);
  float* g_ig = alloc(16384);
  float* g_fg = alloc(16384);
  short* q16 = (short*)alloc(2097152);   // 4096x1024 bf16
  short* k16 = (short*)alloc(2097152);
  short* A16a = (short*)alloc(1048576);  // 4096x512 bf16
  short* A16b = (short*)alloc(1048576);
  short* WT = (short*)alloc(524288);     // up to 2048x512 bf16
  short* Wc16 = (short*)alloc(131072);
  short* Pb16 = (short*)C2;              // 8x1024x1024 bf16 scores (C2 dead then)
  short* VT = (short*)C3;                // 16x256x1024 bf16 V^T (C3 dead then)
  short* H16 = (short*)q16;              // 4096x1024 bf16 (q16 dead then)

  k_embed<<<4096, 128, 0, stream>>>(x, emb, hA);

  auto mlstm = [&](int pi, const float* hin, float* hout) {
    const float* ln = F(pi);       const float* Wup = F(pi + 1);
    const float* convW = F(pi + 2); const float* convb = F(pi + 3);
    const float* Wq = F(pi + 4);   const float* Wk = F(pi + 5);  const float* Wv = F(pi + 6);
    const float* Wi = F(pi + 7);   const float* bi = F(pi + 8);
    const float* Wf = F(pi + 9);   const float* bf_ = F(pi + 10);
    const float* skip = F(pi + 11); const float* onorm = F(pi + 12);
    const float* Wdown = F(pi + 13);

    k_ln512<<<4096, 128, 0, stream>>>(hin, ln, nullptr, A16a);
    k_transp<<<dim3(16, 64, 1), 256, 0, stream>>>(Wup, 0, 0, 2048, WT, 0, 0, 512, 1);
    k_mm<false, false><<<dim3(16, 32, 1), 256, 0, stream>>>(
        A16a, 0, 0, 512, WT, 0, 0, 512, nullptr, 0, 0, 0, X2, 0, 0, 2048, 512, 1);
    k_conv_silu<<<(4096 * 1024) / 256, 256, 0, stream>>>(X2, 2048, 10, convW, convb, C1, nullptr);
    k_qkv<<<4096, 256, 0, stream>>>(C1, X2, Wq, Wk, Wv, C2, C3, C4, q16, k16);
    k_igfg<<<4096, 256, 0, stream>>>(C2, C3, C4, Wi, bi, Wf, bf_, g_ig, g_fg);
    k_gatescan<<<16, 1024, 0, stream>>>(g_ig, g_fg, g_a, g_M, g_e);
    // V^T (per bh: [1024s][256d] stride 1024 -> [256][1024] bf16); C3 (k fp32) is dead after igfg
    k_transp<<<dim3(32, 8, 16), 256, 0, stream>>>(C4, 1048576, 256, 1024, VT, 1048576, 262144, 1024, 4);
    for (int c = 0; c < 2; ++c) {
      const short* qc = q16 + (size_t)c * 2097152;
      const short* kc = k16 + (size_t)c * 2097152;
      k_mm<true, false><<<dim3(8, 8, 8), 256, 0, stream>>>(
          qc, 1048576, 256, 1024, kc, 1048576, 256, 1024,
          nullptr, 0, 0, 0, Pb16, 4194304, 1048576, 1024, 256, 4);
      k_mask<<<dim3(1024, 8), 256, 0, stream>>>(Pb16, g_a, g_M, g_e, c * 8);
      k_mm<false, false><<<dim3(2, 8, 8), 256, 0, stream>>>(
          Pb16, 4194304, 1048576, 1024, VT + (size_t)c * 8 * 262144, 1048576, 262144, 1024,
          nullptr, 0, 0, 0, C5 + (size_t)c * 2097152, 1048576, 256, 1024, 1024, 4);
    }
    k_hncomb<<<4096, 256, 0, stream>>>(C5, C1, X2, onorm, skip, H16);
    k_transp<<<dim3(32, 16, 1), 256, 0, stream>>>(Wdown, 0, 0, 512, WT, 0, 0, 1024, 1);
    k_mm<false, true><<<dim3(4, 32, 1), 256, 0, stream>>>(
        H16, 0, 0, 1024, WT, 0, 0, 1024, hin, 0, 0, 512, hout, 0, 0, 512, 1024, 1);
  };

  auto slstm = [&](const float* hin, float* hout) {
    const float* ln1 = F(30); const float* convW = F(31); const float* convb = F(32);
    const float* Wig = F(33); const float* Wfg = F(34); const float* Wzg = F(35);
    const float* Wog = F(36); const float* Rr = F(37);  const float* bias = F(38);
    const float* gn = F(39);  const float* ln2 = F(40);
    const float* Wu = F(41);  const float* Wd = F(42);

    k_ln512<<<4096, 128, 0, stream>>>(hin, ln1, C3, A16a);                          // xn
    k_conv_silu<<<(4096 * 512) / 256, 256, 0, stream>>>(C3, 512, 9, convW, convb, C4, A16b);  // xc
    k_wcat<<<(4 * 65536) / 256, 256, 0, stream>>>(Wig, Wfg, Wzg, Wog, Wc16);
    k_mm<false, false><<<dim3(1, 32, 8), 256, 0, stream>>>(                          // i,f from xc
        A16b, 128, 0, 512, Wc16, 16384, 65536, 128,
        nullptr, 0, 0, 0, X2, 512, 128, 2048, 128, 2);
    k_mm<false, false><<<dim3(1, 32, 8), 256, 0, stream>>>(                          // z,o from xn
        A16a, 128, 0, 512, Wc16 + 131072, 16384, 65536, 128,
        nullptr, 0, 0, 0, X2 + 256, 512, 128, 2048, 128, 2);
    k_scan<<<16, 512, 0, stream>>>(X2, Rr, bias, C2);
    k_hnadd<<<4096, 512, 0, stream>>>(hin, C2, gn, C3);
    k_ln512<<<4096, 128, 0, stream>>>(C3, ln2, nullptr, A16a);
    k_transp<<<dim3(16, 32, 1), 256, 0, stream>>>(Wu, 0, 0, 1024, WT, 0, 0, 512, 1);
    k_mm<false, false><<<dim3(8, 32, 1), 256, 0, stream>>>(
        A16a, 0, 0, 512, WT, 0, 0, 512, nullptr, 0, 0, 0, C5, 0, 0, 1024, 512, 1);
    k_geluprod<<<(4096 * 512) / 256, 256, 0, stream>>>(C5, A16b);
    k_transp<<<dim3(16, 16, 1), 256, 0, stream>>>(Wd, 0, 0, 512, WT, 0, 0, 512, 1);
    k_mm<false, true><<<dim3(4, 32, 1), 256, 0, stream>>>(
        A16b, 0, 0, 512, WT, 0, 0, 512, C3, 0, 0, 512, hout, 0, 0, 512, 512, 1);
  };

  mlstm(2, hA, hB);
  slstm(hB, hA);
  mlstm(16, hA, hB);
  k_final<<<4, 128, 0, stream>>>(hB, F(43), F(44), F(45), (float*)d_out);
}

// Round 3
// 1943.442 us; speedup vs baseline: 1.3165x; 1.0671x over previous
//
#include <hip/hip_runtime.h>
#include <cstddef>
#include <cstdint>

#define EPSV 1e-5f

typedef __attribute__((ext_vector_type(8))) short bf16x8;  // 8 bf16 = 4 VGPRs
typedef __attribute__((ext_vector_type(4))) float f32x4;
typedef __attribute__((ext_vector_type(2))) float f32x2;

__device__ __forceinline__ short f2bf(float f) {
  union { float f; unsigned u; } v; v.f = f;
  unsigned r = (v.u + 0x7FFFu + ((v.u >> 16) & 1u)) >> 16;  // RNE
  return (short)r;
}
__device__ __forceinline__ float bf2f(short s) {
  union { unsigned u; float f; } v; v.u = ((unsigned)(unsigned short)s) << 16;
  return v.f;
}

__device__ __forceinline__ float wsum(float v) {
  v += __shfl_xor(v, 32, 64);
  v += __shfl_xor(v, 16, 64);
  v += __shfl_xor(v, 8, 64);
  v += __shfl_xor(v, 4, 64);
  v += __shfl_xor(v, 2, 64);
  v += __shfl_xor(v, 1, 64);
  return v;
}

// ---------------------------------------------------------------- embed gather
__global__ __launch_bounds__(128) void k_embed(const int* __restrict__ x,
                                               const float* __restrict__ emb,
                                               float* __restrict__ out) {
  int t = blockIdx.x, tid = threadIdx.x;
  int row = x[t];
  const float4 v = *reinterpret_cast<const float4*>(emb + (size_t)row * 512 + tid * 4);
  *reinterpret_cast<float4*>(out + (size_t)t * 512 + tid * 4) = v;
}

// ---------------------------------------------------------------- layernorm over 512 (fp32 optional + bf16 out)
__global__ __launch_bounds__(128) void k_ln512(const float* __restrict__ in,
                                               const float* __restrict__ w,
                                               float* __restrict__ outf,
                                               short* __restrict__ out16) {
  int t = blockIdx.x, tid = threadIdx.x;
  const float4 v = *reinterpret_cast<const float4*>(in + (size_t)t * 512 + tid * 4);
  float s = v.x + v.y + v.z + v.w;
  float s2 = v.x * v.x + v.y * v.y + v.z * v.z + v.w * v.w;
  s = wsum(s); s2 = wsum(s2);
  __shared__ float l1[2], l2[2];
  int wv = tid >> 6;
  if ((tid & 63) == 0) { l1[wv] = s; l2[wv] = s2; }
  __syncthreads();
  s = l1[0] + l1[1]; s2 = l2[0] + l2[1];
  float mu = s * (1.f / 512.f);
  float var = s2 * (1.f / 512.f) - mu * mu;
  float r = rsqrtf(var + EPSV);
  const float4 w4 = *reinterpret_cast<const float4*>(w + tid * 4);
  float4 o;
  o.x = (v.x - mu) * r * w4.x;
  o.y = (v.y - mu) * r * w4.y;
  o.z = (v.z - mu) * r * w4.z;
  o.w = (v.w - mu) * r * w4.w;
  if (outf) *reinterpret_cast<float4*>(outf + (size_t)t * 512 + tid * 4) = o;
  *reinterpret_cast<short4*>(out16 + (size_t)t * 512 + tid * 4) =
      make_short4(f2bf(o.x), f2bf(o.y), f2bf(o.z), f2bf(o.w));
}

// ---------------------------------------------------------------- bf16 MFMA GEMM, 128x128 tile, BK=64
template <bool OUT16, bool RES>
__global__ __launch_bounds__(256) void k_mm(
    const short* __restrict__ A, size_t sA1, size_t sA2, int lda,
    const short* __restrict__ B, size_t sB1, size_t sB2, int ldb,
    const float* __restrict__ Res, size_t sR1, size_t sR2, int ldr,
    void* __restrict__ Cv, size_t sC1, size_t sC2, int ldc,
    int K, int HB) {
  const int z = blockIdx.z, zh = z / HB, zl = z - zh * HB;
  A += zh * sA1 + zl * sA2;
  B += zh * sB1 + zl * sB2;
  const int bm = blockIdx.y * 128, bn = blockIdx.x * 128;
  const int tid = threadIdx.x, lane = tid & 63, w = tid >> 6;
  const int wr = w >> 1, wc = w & 1;
  const int l15 = lane & 15, l4 = lane >> 4;
  __shared__ short As[128 * 72];
  __shared__ short Bs[128 * 72];
  f32x4 acc[4][4];
#pragma unroll
  for (int i = 0; i < 4; ++i)
#pragma unroll
    for (int j = 0; j < 4; ++j) acc[i][j] = (f32x4){0.f, 0.f, 0.f, 0.f};
  const int srow = tid >> 3, sg = tid & 7;
  for (int k0 = 0; k0 < K; k0 += 64) {
    int4 ra[4], rb[4];
#pragma unroll
    for (int it = 0; it < 4; ++it) {
      int row = it * 32 + srow;
      ra[it] = *reinterpret_cast<const int4*>(A + (size_t)(bm + row) * lda + k0 + sg * 8);
      rb[it] = *reinterpret_cast<const int4*>(B + (size_t)(bn + row) * ldb + k0 + sg * 8);
    }
    __syncthreads();
#pragma unroll
    for (int it = 0; it < 4; ++it) {
      int row = it * 32 + srow;
      *reinterpret_cast<int4*>(As + row * 72 + sg * 8) = ra[it];
      *reinterpret_cast<int4*>(Bs + row * 72 + sg * 8) = rb[it];
    }
    __syncthreads();
#pragma unroll
    for (int kk = 0; kk < 2; ++kk) {
      bf16x8 af[4], bfr[4];
#pragma unroll
      for (int i = 0; i < 4; ++i) {
        af[i]  = *reinterpret_cast<const bf16x8*>(As + (wr * 64 + i * 16 + l15) * 72 + kk * 32 + l4 * 8);
        bfr[i] = *reinterpret_cast<const bf16x8*>(Bs + (wc * 64 + i * 16 + l15) * 72 + kk * 32 + l4 * 8);
      }
#pragma unroll
      for (int i = 0; i < 4; ++i)
#pragma unroll
        for (int j = 0; j < 4; ++j)
          acc[i][j] = __builtin_amdgcn_mfma_f32_16x16x32_bf16(af[i], bfr[j], acc[i][j], 0, 0, 0);
    }
  }
  const int row0 = bm + wr * 64 + l4 * 4, col0 = bn + wc * 64 + l15;
  if constexpr (OUT16) {
    short* C = (short*)Cv + zh * sC1 + zl * sC2;
#pragma unroll
    for (int mi = 0; mi < 4; ++mi)
#pragma unroll
      for (int r = 0; r < 4; ++r) {
        size_t ro = (size_t)(row0 + mi * 16 + r) * ldc;
#pragma unroll
        for (int ni = 0; ni < 4; ++ni) C[ro + col0 + ni * 16] = f2bf(acc[mi][ni][r]);
      }
  } else {
    float* C = (float*)Cv + zh * sC1 + zl * sC2;
    const float* Rp = Res ? (Res + zh * sR1 + zl * sR2) : nullptr;
#pragma unroll
    for (int mi = 0; mi < 4; ++mi)
#pragma unroll
      for (int r = 0; r < 4; ++r) {
        int rw = row0 + mi * 16 + r;
#pragma unroll
        for (int ni = 0; ni < 4; ++ni) {
          float vv = acc[mi][ni][r];
          if constexpr (RES) vv += Rp[(size_t)rw * ldr + col0 + ni * 16];
          C[(size_t)rw * ldc + col0 + ni * 16] = vv;
        }
      }
  }
}

// ---------------------------------------------------------------- transpose-convert fp32[R][C] -> bf16[C][R]
__global__ __launch_bounds__(256) void k_transp(const float* __restrict__ in, size_t sI1, size_t sI2, int ldi,
                                                short* __restrict__ out, size_t sO1, size_t sO2, int ldo,
                                                int HB) {
  __shared__ float t[32][33];
  int z = blockIdx.z, zh = z / HB, zl = z - zh * HB;
  in += zh * sI1 + zl * sI2;
  out += zh * sO1 + zl * sO2;
  int r0 = blockIdx.x * 32, c0 = blockIdx.y * 32;
  int tx = threadIdx.x & 31, ty = threadIdx.x >> 5;
#pragma unroll
  for (int i = 0; i < 4; ++i) {
    int rr = ty + i * 8;
    t[rr][tx] = in[(size_t)(r0 + rr) * ldi + c0 + tx];
  }
  __syncthreads();
#pragma unroll
  for (int i = 0; i < 4; ++i) {
    int cr = ty + i * 8;
    out[(size_t)(c0 + cr) * ldo + r0 + tx] = f2bf(t[tx][cr]);
  }
}

// ---------------------------------------------------------------- causal depthwise conv(K=3)+silu (+bf16 out)
__global__ __launch_bounds__(256) void k_conv_silu(const float* __restrict__ in, int inLd, int logC,
                                                   const float* __restrict__ w,
                                                   const float* __restrict__ bias,
                                                   float* __restrict__ out,
                                                   short* __restrict__ out16) {
  int idx = blockIdx.x * 256 + threadIdx.x;
  int C = 1 << logC;
  int t = idx >> logC, c = idx & (C - 1);
  int s = t & 1023;
  const float* ip = in + (size_t)t * inLd + c;
  float acc = bias[c] + w[c * 3 + 2] * ip[0];
  if (s >= 1) acc += w[c * 3 + 1] * ip[-(ptrdiff_t)inLd];
  if (s >= 2) acc += w[c * 3 + 0] * ip[-2 * (ptrdiff_t)inLd];
  float r = acc / (1.f + __expf(-acc));
  out[(size_t)t * C + c] = r;
  if (out16) out16[(size_t)t * C + c] = f2bf(r);
}

// ---------------------------------------------------------------- block-diagonal q,k,v (4x4 blocks) + bf16 q,k
__global__ __launch_bounds__(256) void k_qkv(const float* __restrict__ xc, const float* __restrict__ x2,
                                             const float* __restrict__ Wq, const float* __restrict__ Wk,
                                             const float* __restrict__ Wv,
                                             float* __restrict__ q, float* __restrict__ k,
                                             float* __restrict__ v,
                                             short* __restrict__ q16, short* __restrict__ k16) {
  int t = blockIdx.x, n = threadIdx.x;
  const float4 xcv = *reinterpret_cast<const float4*>(xc + (size_t)t * 1024 + n * 4);
  const float4 xmv = *reinterpret_cast<const float4*>(x2 + (size_t)t * 2048 + n * 4);
  float qa[4], ka[4], va[4];
#pragma unroll
  for (int o = 0; o < 4; ++o) {
    const float4 wq = *reinterpret_cast<const float4*>(Wq + n * 16 + o * 4);
    const float4 wk = *reinterpret_cast<const float4*>(Wk + n * 16 + o * 4);
    const float4 wv = *reinterpret_cast<const float4*>(Wv + n * 16 + o * 4);
    qa[o] = xcv.x * wq.x + xcv.y * wq.y + xcv.z * wq.z + xcv.w * wq.w;
    ka[o] = xcv.x * wk.x + xcv.y * wk.y + xcv.z * wk.z + xcv.w * wk.w;
    va[o] = xmv.x * wv.x + xmv.y * wv.y + xmv.z * wv.z + xmv.w * wv.w;
  }
  *reinterpret_cast<float4*>(q + (size_t)t * 1024 + n * 4) = make_float4(qa[0], qa[1], qa[2], qa[3]);
  *reinterpret_cast<float4*>(k + (size_t)t * 1024 + n * 4) = make_float4(ka[0], ka[1], ka[2], ka[3]);
  *reinterpret_cast<float4*>(v + (size_t)t * 1024 + n * 4) = make_float4(va[0], va[1], va[2], va[3]);
  *reinterpret_cast<short4*>(q16 + (size_t)t * 1024 + n * 4) =
      make_short4(f2bf(qa[0]), f2bf(qa[1]), f2bf(qa[2]), f2bf(qa[3]));
  *reinterpret_cast<short4*>(k16 + (size_t)t * 1024 + n * 4) =
      make_short4(f2bf(ka[0]), f2bf(ka[1]), f2bf(ka[2]), f2bf(ka[3]));
}

// ---------------------------------------------------------------- ig/fg = qkv @ Wi/Wf + bias, layout [b*4+h][s]
__global__ __launch_bounds__(256) void k_igfg(const float* __restrict__ q, const float* __restrict__ k,
                                              const float* __restrict__ v,
                                              const float* __restrict__ Wi, const float* __restrict__ bi,
                                              const float* __restrict__ Wf, const float* __restrict__ bf,
                                              float* __restrict__ ig, float* __restrict__ fg) {
  int t = blockIdx.x, tid = threadIdx.x;
  float aI[4] = {0.f, 0.f, 0.f, 0.f}, aF[4] = {0.f, 0.f, 0.f, 0.f};
  for (int c = tid; c < 1024; c += 256) {
    float qv = q[(size_t)t * 1024 + c];
    float kv = k[(size_t)t * 1024 + c];
    float vv = v[(size_t)t * 1024 + c];
    const float4 wiq = *reinterpret_cast<const float4*>(Wi + (size_t)c * 4);
    const float4 wik = *reinterpret_cast<const float4*>(Wi + (size_t)(1024 + c) * 4);
    const float4 wiv = *reinterpret_cast<const float4*>(Wi + (size_t)(2048 + c) * 4);
    const float4 wfq = *reinterpret_cast<const float4*>(Wf + (size_t)c * 4);
    const float4 wfk = *reinterpret_cast<const float4*>(Wf + (size_t)(1024 + c) * 4);
    const float4 wfv = *reinterpret_cast<const float4*>(Wf + (size_t)(2048 + c) * 4);
    aI[0] += qv * wiq.x + kv * wik.x + vv * wiv.x;
    aI[1] += qv * wiq.y + kv * wik.y + vv * wiv.y;
    aI[2] += qv * wiq.z + kv * wik.z + vv * wiv.z;
    aI[3] += qv * wiq.w + kv * wik.w + vv * wiv.w;
    aF[0] += qv * wfq.x + kv * wfk.x + vv * wfv.x;
    aF[1] += qv * wfq.y + kv * wfk.y + vv * wfv.y;
    aF[2] += qv * wfq.z + kv * wfk.z + vv * wfv.z;
    aF[3] += qv * wfq.w + kv * wfk.w + vv * wfv.w;
  }
#pragma unroll
  for (int h = 0; h < 4; ++h) { aI[h] = wsum(aI[h]); aF[h] = wsum(aF[h]); }
  __shared__ float red[2][4][4];
  int wv = tid >> 6;
  if ((tid & 63) == 0) {
#pragma unroll
    for (int h = 0; h < 4; ++h) { red[0][wv][h] = aI[h]; red[1][wv][h] = aF[h]; }
  }
  __syncthreads();
  if (tid < 8) {
    int which = tid >> 2, h = tid & 3;
    float sum = red[which][0][h] + red[which][1][h] + red[which][2][h] + red[which][3][h];
    int b = t >> 10, s = t & 1023;
    size_t o = (size_t)(b * 4 + h) * 1024 + s;
    if (which == 0) ig[o] = sum + bi[h];
    else            fg[o] = sum + bf[h];
  }
}

// ---------------------------------------------------------------- per-(b,h) gate scans
__global__ __launch_bounds__(1024) void k_gatescan(const float* __restrict__ ig, const float* __restrict__ fg,
                                                   float* __restrict__ a, float* __restrict__ Mx,
                                                   float* __restrict__ emax) {
  int bh = blockIdx.x, s = threadIdx.x;
  size_t o = (size_t)bh * 1024 + s;
  float f = fg[o];
  float lf = (f >= 0.f) ? -log1pf(__expf(-f)) : (f - log1pf(__expf(f)));
  __shared__ float buf[1024];
  float val = lf;
  buf[s] = val;
  __syncthreads();
#pragma unroll
  for (int off = 1; off < 1024; off <<= 1) {
    float add = (s >= off) ? buf[s - off] : 0.f;
    __syncthreads();
    val += add; buf[s] = val;
    __syncthreads();
  }
  float csv = val;
  float av = ig[o] - csv;
  float mv = av;
  buf[s] = mv;
  __syncthreads();
#pragma unroll
  for (int off = 1; off < 1024; off <<= 1) {
    float other = (s >= off) ? buf[s - off] : -3.4e38f;
    __syncthreads();
    mv = fmaxf(mv, other); buf[s] = mv;
    __syncthreads();
  }
  a[o] = av;
  Mx[o] = mv;
  emax[o] = __expf(-(csv + mv));
}

// ---------------------------------------------------------------- mask+gate-weight+row-normalize (bf16, in place)
__global__ __launch_bounds__(256) void k_mask(short* __restrict__ P, const float* __restrict__ a,
                                              const float* __restrict__ Mx, const float* __restrict__ emax,
                                              int bhBase) {
  int i = blockIdx.x, z = blockIdx.y, tid = threadIdx.x;
  int bh = bhBase + z;
  short* Prow = P + ((size_t)z * 1024 + i) * 1024;
  const float* ab = a + (size_t)bh * 1024;
  float Mi = Mx[(size_t)bh * 1024 + i];
  float vals[4];
  float rs = 0.f;
#pragma unroll
  for (int jj = 0; jj < 4; ++jj) {
    int j = tid + jj * 256;
    float pv = 0.f;
    if (j <= i) pv = bf2f(Prow[j]) * 0.0625f * __expf(ab[j] - Mi);
    vals[jj] = pv;
    rs += pv;
  }
  rs = wsum(rs);
  __shared__ float red[4];
  if ((tid & 63) == 0) red[tid >> 6] = rs;
  __syncthreads();
  float tot = red[0] + red[1] + red[2] + red[3];
  float norm = fmaxf(fabsf(tot), emax[(size_t)bh * 1024 + i]) + 1e-6f;
  float inv = 1.f / norm;
#pragma unroll
  for (int jj = 0; jj < 4; ++jj) Prow[tid + jj * 256] = f2bf(vals[jj] * inv);
}

// ---------------------------------------------------------------- mLSTM headnorm + skip + silu(z) combine -> bf16
__global__ __launch_bounds__(256) void k_hncomb(const float* __restrict__ hattn, const float* __restrict__ xc,
                                                const float* __restrict__ x2, const float* __restrict__ onorm,
                                                const float* __restrict__ skip, short* __restrict__ out) {
  int t = blockIdx.x, tid = threadIdx.x;
  int w = tid >> 6, lane = tid & 63;
  int cbase = w * 256 + lane * 4;
  const float4 v = *reinterpret_cast<const float4*>(hattn + (size_t)t * 1024 + cbase);
  float s = v.x + v.y + v.z + v.w;
  float s2 = v.x * v.x + v.y * v.y + v.z * v.z + v.w * v.w;
  s = wsum(s); s2 = wsum(s2);
  float mu = s * (1.f / 256.f), var = s2 * (1.f / 256.f) - mu * mu;
  float r = rsqrtf(var + EPSV);
  const float4 on4 = *reinterpret_cast<const float4*>(onorm + cbase);
  const float4 sk4 = *reinterpret_cast<const float4*>(skip + cbase);
  const float4 xc4 = *reinterpret_cast<const float4*>(xc + (size_t)t * 1024 + cbase);
  const float4 z4 = *reinterpret_cast<const float4*>(x2 + (size_t)t * 2048 + 1024 + cbase);
  float4 o;
  o.x = ((v.x - mu) * r * on4.x + sk4.x * xc4.x) * (z4.x / (1.f + __expf(-z4.x)));
  o.y = ((v.y - mu) * r * on4.y + sk4.y * xc4.y) * (z4.y / (1.f + __expf(-z4.y)));
  o.z = ((v.z - mu) * r * on4.z + sk4.z * xc4.z) * (z4.z / (1.f + __expf(-z4.z)));
  o.w = ((v.w - mu) * r * on4.w + sk4.w * xc4.w) * (z4.w / (1.f + __expf(-z4.w)));
  *reinterpret_cast<short4*>(out + (size_t)t * 1024 + cbase) =
      make_short4(f2bf(o.x), f2bf(o.y), f2bf(o.z), f2bf(o.w));
}

// ---------------------------------------------------------------- concat+convert sLSTM gate weights -> bf16
__global__ __launch_bounds__(256) void k_wcat(const float* __restrict__ wi, const float* __restrict__ wf,
                                              const float* __restrict__ wz, const float* __restrict__ wo,
                                              short* __restrict__ Wcat) {
  int idx = blockIdx.x * 256 + threadIdx.x;
  int g = idx >> 16, r = idx & 65535;
  const float* s = (g == 0) ? wi : ((g == 1) ? wf : ((g == 2) ? wz : wo));
  Wcat[idx] = f2bf(s[r]);
}

// ---------------------------------------------------------------- sLSTM sequential scan, one block per (b,h)
// 512 threads, one per (gate g, element e). R column (128 f32) lives in VGPRs.
// One barrier/step via double-buffered y; raws exchanged with 2 intra-quad shuffles.
__global__ __launch_bounds__(512, 1) void k_scan(const float* __restrict__ Wx, const float* __restrict__ R,
                                                 const float* __restrict__ bias, float* __restrict__ ys) {
  int bh = blockIdx.x, b = bh >> 2, h = bh & 3;
  int tid = threadIdx.x;
  int e = tid >> 2, g = tid & 3;
  // rc[i] = { R[h][2i][g*128+e], R[h][2i+1][g*128+e] }
  f32x2 rc[64];
  {
    const float* Rp = R + (size_t)h * 65536 + g * 128 + e;
#pragma unroll
    for (int i = 0; i < 64; ++i) {
      rc[i][0] = Rp[(size_t)(2 * i) * 512];
      rc[i][1] = Rp[(size_t)(2 * i + 1) * 512];
    }
  }
  const float bsv = bias[(size_t)g * 512 + h * 128 + e];
  const float* wxp = Wx + (size_t)b * 1024 * 2048 + h * 512 + g * 128 + e;
  __shared__ float ysh[2][128];
  if (tid < 128) { ysh[0][tid] = 0.f; ysh[1][tid] = 0.f; }
  float c_ = 0.f, n_ = 0.f, m_ = 0.f;
  float wx = wxp[0];
  float* ysg = ys + ((size_t)b * 1024) * 512 + h * 128 + e;
  __syncthreads();
  for (int s = 0; s < 1024; ++s) {
    const float* yb = &ysh[(s + 1) & 1][0];   // y_{s-1}
    // prefetch next step's Wx (off critical path)
    int sp = (s + 1 < 1024) ? (s + 1) : 1023;
    float wxn = wxp[(size_t)sp * 2048];
    // 128-deep dot: 64 packed f32x2 FMAs, 4 independent chains
    f32x2 accA = {0.f, 0.f}, accB = {0.f, 0.f};
#pragma unroll
    for (int i = 0; i < 32; ++i) {
      const f32x2 y0 = *reinterpret_cast<const f32x2*>(yb + i * 4);
      const f32x2 y1 = *reinterpret_cast<const f32x2*>(yb + i * 4 + 2);
      accA = y0 * rc[2 * i] + accA;
      accB = y1 * rc[2 * i + 1] + accB;
    }
    float raw = ((accA[0] + accB[0]) + (accA[1] + accB[1])) + wx + bsv;
    // exchange raws within the quad (lanes 4k..4k+3 share e)
    float o1 = __shfl_xor(raw, 1, 64);
    float o2 = __shfl_xor(raw, 2, 64);
    float o3 = __shfl_xor(o1, 2, 64);
    // var k holds tag g^k; raw[j] = var[g^j]
    const bool g0 = (g & 1) != 0, g1 = (g & 2) != 0;
    float ir  = g1 ? (g0 ? o3 : o2) : (g0 ? o1 : raw);
    float fr  = g1 ? (g0 ? o2 : o3) : (g0 ? raw : o1);
    float zr  = g1 ? (g0 ? o1 : raw) : (g0 ? o3 : o2);
    float orr = g1 ? (g0 ? raw : o1) : (g0 ? o2 : o3);
    // gate chain (redundant per quad — keeps it off cross-thread path)
    float lsf = (fr >= 0.f) ? -__logf(1.f + __expf(-fr)) : (fr - __logf(1.f + __expf(fr)));
    float lfm = m_ + lsf;
    float mn = fmaxf(ir, lfm);
    float igt = __expf(ir - mn);
    float fgt = __expf(lfm - mn);
    float t2 = __expf(-2.f * fabsf(zr));
    float th = (1.f - t2) / (1.f + t2);
    th = (zr >= 0.f) ? th : -th;
    float cn = fgt * c_ + igt * th;
    float nn = fgt * n_ + igt;
    float yn = cn / (nn * (1.f + __expf(-orr)));
    c_ = cn; n_ = nn; m_ = mn;
    if (g == 0) {
      ysh[s & 1][e] = yn;
      ysg[(size_t)s * 512] = yn;
    }
    wx = wxn;
    __syncthreads();
  }
}

// ---------------------------------------------------------------- sLSTM headnorm(128)+gn + residual
__global__ __launch_bounds__(512) void k_hnadd(const float* __restrict__ hin, const float* __restrict__ ysv,
                                               const float* __restrict__ gn, float* __restrict__ out) {
  int t = blockIdx.x, tid = threadIdx.x;
  float yv = ysv[(size_t)t * 512 + tid];
  float s = wsum(yv), s2 = wsum(yv * yv);
  __shared__ float l1[8], l2[8];
  int wv = tid >> 6;
  if ((tid & 63) == 0) { l1[wv] = s; l2[wv] = s2; }
  __syncthreads();
  int h2 = (tid >> 7) * 2;
  float S = l1[h2] + l1[h2 + 1], S2 = l2[h2] + l2[h2 + 1];
  float mu = S * (1.f / 128.f), var = S2 * (1.f / 128.f) - mu * mu;
  float r = rsqrtf(var + EPSV);
  out[(size_t)t * 512 + tid] = hin[(size_t)t * 512 + tid] + (yv - mu) * r * gn[tid];
}

// ---------------------------------------------------------------- gelu(g)*up -> bf16
__global__ __launch_bounds__(256) void k_geluprod(const float* __restrict__ u, short* __restrict__ gp) {
  int idx = blockIdx.x * 256 + threadIdx.x;
  int t = idx >> 9, c = idx & 511;
  float g = u[(size_t)t * 1024 + c];
  float up = u[(size_t)t * 1024 + 512 + c];
  float ge = 0.5f * g * (1.f + erff(g * 0.70710678118654752f));
  gp[idx] = f2bf(ge * up);
}

// ---------------------------------------------------------------- final LN(last token) + classifier
__global__ __launch_bounds__(128) void k_final(const float* __restrict__ h, const float* __restrict__ w,
                                               const float* __restrict__ cw, const float* __restrict__ cb,
                                               float* __restrict__ out) {
  int b = blockIdx.x, tid = threadIdx.x;
  const float* row = h + ((size_t)(b * 1024 + 1023)) * 512;
  const float4 v = *reinterpret_cast<const float4*>(row + tid * 4);
  float s = v.x + v.y + v.z + v.w;
  float s2 = v.x * v.x + v.y * v.y + v.z * v.z + v.w * v.w;
  s = wsum(s); s2 = wsum(s2);
  __shared__ float l1[2], l2[2];
  int wv = tid >> 6;
  if ((tid & 63) == 0) { l1[wv] = s; l2[wv] = s2; }
  __syncthreads();
  s = l1[0] + l1[1]; s2 = l2[0] + l2[1];
  float mu = s * (1.f / 512.f);
  float var = s2 * (1.f / 512.f) - mu * mu;
  float r = rsqrtf(var + EPSV);
  const float4 w4 = *reinterpret_cast<const float4*>(w + tid * 4);
  const float4 c4 = *reinterpret_cast<const float4*>(cw + tid * 4);
  float d = (v.x - mu) * r * w4.x * c4.x + (v.y - mu) * r * w4.y * c4.y +
            (v.z - mu) * r * w4.z * c4.z + (v.w - mu) * r * w4.w * c4.w;
  d = wsum(d);
  __syncthreads();
  if ((tid & 63) == 0) l1[tid >> 6] = d;
  __syncthreads();
  if (tid == 0) out[b] = l1[0] + l1[1] + cb[0];
}

// ================================================================ host
extern "C" void kernel_launch(void* const* d_in, const int* in_sizes, int n_in,
                              void* d_out, int out_size, void* d_ws, size_t ws_size,
                              hipStream_t stream) {
  (void)in_sizes; (void)n_in; (void)out_size; (void)ws_size;
  auto F = [&](int i) { return (const float*)d_in[i]; };
  const int* x = (const int*)d_in[0];
  const float* emb = F(1);

  float* ws = (float*)d_ws;
  size_t off = 0;
  auto alloc = [&](size_t n) { float* p = ws + off; off += n; return p; };
  float* hA = alloc(2097152);
  float* hB = alloc(2097152);
  float* X2 = alloc(8388608);
  float* C1 = alloc(4194304);
  float* C2 = alloc(4194304);
  float* C3 = alloc(4194304);
  float* C4 = alloc(4194304);
  float* C5 = alloc(4194304);
  float* g_a = alloc(16384);
  float* g_M = alloc(16384);
  float* g_e = alloc(16384);
  float* g_ig = alloc(16384);
  float* g_fg = alloc(16384);
  short* q16 = (short*)alloc(2097152);   // 4096x1024 bf16
  short* k16 = (short*)alloc(2097152);
  short* A16a = (short*)alloc(1048576);  // 4096x512 bf16
  short* A16b = (short*)alloc(1048576);
  short* WT = (short*)alloc(524288);     // up to 2048x512 bf16
  short* Wc16 = (short*)alloc(131072);
  short* Pb16 = (short*)C2;              // 8x1024x1024 bf16 scores (C2 dead then)
  short* VT = (short*)C3;                // 16x256x1024 bf16 V^T (C3 dead then)
  short* H16 = (short*)q16;              // 4096x1024 bf16 (q16 dead then)

  k_embed<<<4096, 128, 0, stream>>>(x, emb, hA);

  auto mlstm = [&](int pi, const float* hin, float* hout) {
    const float* ln = F(pi);       const float* Wup = F(pi + 1);
    const float* convW = F(pi + 2); const float* convb = F(pi + 3);
    const float* Wq = F(pi + 4);   const float* Wk = F(pi + 5);  const float* Wv = F(pi + 6);
    const float* Wi = F(pi + 7);   const float* bi = F(pi + 8);
    const float* Wf = F(pi + 9);   const float* bf_ = F(pi + 10);
    const float* skip = F(pi + 11); const float* onorm = F(pi + 12);
    const float* Wdown = F(pi + 13);

    k_ln512<<<4096, 128, 0, stream>>>(hin, ln, nullptr, A16a);
    k_transp<<<dim3(16, 64, 1), 256, 0, stream>>>(Wup, 0, 0, 2048, WT, 0, 0, 512, 1);
    k_mm<false, false><<<dim3(16, 32, 1), 256, 0, stream>>>(
        A16a, 0, 0, 512, WT, 0, 0, 512, nullptr, 0, 0, 0, X2, 0, 0, 2048, 512, 1);
    k_conv_silu<<<(4096 * 1024) / 256, 256, 0, stream>>>(X2, 2048, 10, convW, convb, C1, nullptr);
    k_qkv<<<4096, 256, 0, stream>>>(C1, X2, Wq, Wk, Wv, C2, C3, C4, q16, k16);
    k_igfg<<<4096, 256, 0, stream>>>(C2, C3, C4, Wi, bi, Wf, bf_, g_ig, g_fg);
    k_gatescan<<<16, 1024, 0, stream>>>(g_ig, g_fg, g_a, g_M, g_e);
    // V^T (per bh: [1024s][256d] stride 1024 -> [256][1024] bf16); C3 (k fp32) is dead after igfg
    k_transp<<<dim3(32, 8, 16), 256, 0, stream>>>(C4, 1048576, 256, 1024, VT, 1048576, 262144, 1024, 4);
    for (int c = 0; c < 2; ++c) {
      const short* qc = q16 + (size_t)c * 2097152;
      const short* kc = k16 + (size_t)c * 2097152;
      k_mm<true, false><<<dim3(8, 8, 8), 256, 0, stream>>>(
          qc, 1048576, 256, 1024, kc, 1048576, 256, 1024,
          nullptr, 0, 0, 0, Pb16, 4194304, 1048576, 1024, 256, 4);
      k_mask<<<dim3(1024, 8), 256, 0, stream>>>(Pb16, g_a, g_M, g_e, c * 8);
      k_mm<false, false><<<dim3(2, 8, 8), 256, 0, stream>>>(
          Pb16, 4194304, 1048576, 1024, VT + (size_t)c * 8 * 262144, 1048576, 262144, 1024,
          nullptr, 0, 0, 0, C5 + (size_t)c * 2097152, 1048576, 256, 1024, 1024, 4);
    }
    k_hncomb<<<4096, 256, 0, stream>>>(C5, C1, X2, onorm, skip, H16);
    k_transp<<<dim3(32, 16, 1), 256, 0, stream>>>(Wdown, 0, 0, 512, WT, 0, 0, 1024, 1);
    k_mm<false, true><<<dim3(4, 32, 1), 256, 0, stream>>>(
        H16, 0, 0, 1024, WT, 0, 0, 1024, hin, 0, 0, 512, hout, 0, 0, 512, 1024, 1);
  };

  auto slstm = [&](const float* hin, float* hout) {
    const float* ln1 = F(30); const float* convW = F(31); const float* convb = F(32);
    const float* Wig = F(33); const float* Wfg = F(34); const float* Wzg = F(35);
    const float* Wog = F(36); const float* Rr = F(37);  const float* bias = F(38);
    const float* gn = F(39);  const float* ln2 = F(40);
    const float* Wu = F(41);  const float* Wd = F(42);

    k_ln512<<<4096, 128, 0, stream>>>(hin, ln1, C3, A16a);                          // xn
    k_conv_silu<<<(4096 * 512) / 256, 256, 0, stream>>>(C3, 512, 9, convW, convb, C4, A16b);  // xc
    k_wcat<<<(4 * 65536) / 256, 256, 0, stream>>>(Wig, Wfg, Wzg, Wog, Wc16);
    k_mm<false, false><<<dim3(1, 32, 8), 256, 0, stream>>>(                          // i,f from xc
        A16b, 128, 0, 512, Wc16, 16384, 65536, 128,
        nullptr, 0, 0, 0, X2, 512, 128, 2048, 128, 2);
    k_mm<false, false><<<dim3(1, 32, 8), 256, 0, stream>>>(                          // z,o from xn
        A16a, 128, 0, 512, Wc16 + 131072, 16384, 65536, 128,
        nullptr, 0, 0, 0, X2 + 256, 512, 128, 2048, 128, 2);
    k_scan<<<16, 512, 0, stream>>>(X2, Rr, bias, C2);
    k_hnadd<<<4096, 512, 0, stream>>>(hin, C2, gn, C3);
    k_ln512<<<4096, 128, 0, stream>>>(C3, ln2, nullptr, A16a);
    k_transp<<<dim3(16, 32, 1), 256, 0, stream>>>(Wu, 0, 0, 1024, WT, 0, 0, 512, 1);
    k_mm<false, false><<<dim3(8, 32, 1), 256, 0, stream>>>(
        A16a, 0, 0, 512, WT, 0, 0, 512, nullptr, 0, 0, 0, C5, 0, 0, 1024, 512, 1);
    k_geluprod<<<(4096 * 512) / 256, 256, 0, stream>>>(C5, A16b);
    k_transp<<<dim3(16, 16, 1), 256, 0, stream>>>(Wd, 0, 0, 512, WT, 0, 0, 512, 1);
    k_mm<false, true><<<dim3(4, 32, 1), 256, 0, stream>>>(
        A16b, 0, 0, 512, WT, 0, 0, 512, C3, 0, 0, 512, hout, 0, 0, 512, 512, 1);
  };

  mlstm(2, hA, hB);
  slstm(hB, hA);
  mlstm(16, hA, hB);
  k_final<<<4, 128, 0, stream>>>(hB, F(43), F(44), F(45), (float*)d_out);
}

// Round 9
// 1892.232 us; speedup vs baseline: 1.3522x; 1.0271x over previous
//
#include <hip/hip_runtime.h>
#include <cstddef>
#include <cstdint>

#define EPSV 1e-5f

typedef __attribute__((ext_vector_type(8))) short bf16x8;  // 8 bf16 = 4 VGPRs
typedef __attribute__((ext_vector_type(4))) float f32x4;
typedef __attribute__((ext_vector_type(2))) float f32x2;

__device__ __forceinline__ short f2bf(float f) {
  union { float f; unsigned u; } v; v.f = f;
  unsigned r = (v.u + 0x7FFFu + ((v.u >> 16) & 1u)) >> 16;  // RNE
  return (short)r;
}
__device__ __forceinline__ float bf2f(short s) {
  union { unsigned u; float f; } v; v.u = ((unsigned)(unsigned short)s) << 16;
  return v.f;
}

__device__ __forceinline__ float wsum(float v) {
  v += __shfl_xor(v, 32, 64);
  v += __shfl_xor(v, 16, 64);
  v += __shfl_xor(v, 8, 64);
  v += __shfl_xor(v, 4, 64);
  v += __shfl_xor(v, 2, 64);
  v += __shfl_xor(v, 1, 64);
  return v;
}

// ---------------------------------------------------------------- embed gather
__global__ __launch_bounds__(128) void k_embed(const int* __restrict__ x,
                                               const float* __restrict__ emb,
                                               float* __restrict__ out) {
  int t = blockIdx.x, tid = threadIdx.x;
  int row = x[t];
  const float4 v = *reinterpret_cast<const float4*>(emb + (size_t)row * 512 + tid * 4);
  *reinterpret_cast<float4*>(out + (size_t)t * 512 + tid * 4) = v;
}

// ---------------------------------------------------------------- layernorm over 512 (fp32 optional + bf16 out)
__global__ __launch_bounds__(128) void k_ln512(const float* __restrict__ in,
                                               const float* __restrict__ w,
                                               float* __restrict__ outf,
                                               short* __restrict__ out16) {
  int t = blockIdx.x, tid = threadIdx.x;
  const float4 v = *reinterpret_cast<const float4*>(in + (size_t)t * 512 + tid * 4);
  float s = v.x + v.y + v.z + v.w;
  float s2 = v.x * v.x + v.y * v.y + v.z * v.z + v.w * v.w;
  s = wsum(s); s2 = wsum(s2);
  __shared__ float l1[2], l2[2];
  int wv = tid >> 6;
  if ((tid & 63) == 0) { l1[wv] = s; l2[wv] = s2; }
  __syncthreads();
  s = l1[0] + l1[1]; s2 = l2[0] + l2[1];
  float mu = s * (1.f / 512.f);
  float var = s2 * (1.f / 512.f) - mu * mu;
  float r = rsqrtf(var + EPSV);
  const float4 w4 = *reinterpret_cast<const float4*>(w + tid * 4);
  float4 o;
  o.x = (v.x - mu) * r * w4.x;
  o.y = (v.y - mu) * r * w4.y;
  o.z = (v.z - mu) * r * w4.z;
  o.w = (v.w - mu) * r * w4.w;
  if (outf) *reinterpret_cast<float4*>(outf + (size_t)t * 512 + tid * 4) = o;
  *reinterpret_cast<short4*>(out16 + (size_t)t * 512 + tid * 4) =
      make_short4(f2bf(o.x), f2bf(o.y), f2bf(o.z), f2bf(o.w));
}

// ---------------------------------------------------------------- bf16 MFMA GEMM, 128x128 tile, BK=64
template <bool OUT16, bool RES>
__global__ __launch_bounds__(256) void k_mm(
    const short* __restrict__ A, size_t sA1, size_t sA2, int lda,
    const short* __restrict__ B, size_t sB1, size_t sB2, int ldb,
    const float* __restrict__ Res, size_t sR1, size_t sR2, int ldr,
    void* __restrict__ Cv, size_t sC1, size_t sC2, int ldc,
    int K, int HB) {
  const int z = blockIdx.z, zh = z / HB, zl = z - zh * HB;
  A += zh * sA1 + zl * sA2;
  B += zh * sB1 + zl * sB2;
  const int bm = blockIdx.y * 128, bn = blockIdx.x * 128;
  const int tid = threadIdx.x, lane = tid & 63, w = tid >> 6;
  const int wr = w >> 1, wc = w & 1;
  const int l15 = lane & 15, l4 = lane >> 4;
  __shared__ short As[128 * 72];
  __shared__ short Bs[128 * 72];
  f32x4 acc[4][4];
#pragma unroll
  for (int i = 0; i < 4; ++i)
#pragma unroll
    for (int j = 0; j < 4; ++j) acc[i][j] = (f32x4){0.f, 0.f, 0.f, 0.f};
  const int srow = tid >> 3, sg = tid & 7;
  for (int k0 = 0; k0 < K; k0 += 64) {
    int4 ra[4], rb[4];
#pragma unroll
    for (int it = 0; it < 4; ++it) {
      int row = it * 32 + srow;
      ra[it] = *reinterpret_cast<const int4*>(A + (size_t)(bm + row) * lda + k0 + sg * 8);
      rb[it] = *reinterpret_cast<const int4*>(B + (size_t)(bn + row) * ldb + k0 + sg * 8);
    }
    __syncthreads();
#pragma unroll
    for (int it = 0; it < 4; ++it) {
      int row = it * 32 + srow;
      *reinterpret_cast<int4*>(As + row * 72 + sg * 8) = ra[it];
      *reinterpret_cast<int4*>(Bs + row * 72 + sg * 8) = rb[it];
    }
    __syncthreads();
#pragma unroll
    for (int kk = 0; kk < 2; ++kk) {
      bf16x8 af[4], bfr[4];
#pragma unroll
      for (int i = 0; i < 4; ++i) {
        af[i]  = *reinterpret_cast<const bf16x8*>(As + (wr * 64 + i * 16 + l15) * 72 + kk * 32 + l4 * 8);
        bfr[i] = *reinterpret_cast<const bf16x8*>(Bs + (wc * 64 + i * 16 + l15) * 72 + kk * 32 + l4 * 8);
      }
#pragma unroll
      for (int i = 0; i < 4; ++i)
#pragma unroll
        for (int j = 0; j < 4; ++j)
          acc[i][j] = __builtin_amdgcn_mfma_f32_16x16x32_bf16(af[i], bfr[j], acc[i][j], 0, 0, 0);
    }
  }
  const int row0 = bm + wr * 64 + l4 * 4, col0 = bn + wc * 64 + l15;
  if constexpr (OUT16) {
    short* C = (short*)Cv + zh * sC1 + zl * sC2;
#pragma unroll
    for (int mi = 0; mi < 4; ++mi)
#pragma unroll
      for (int r = 0; r < 4; ++r) {
        size_t ro = (size_t)(row0 + mi * 16 + r) * ldc;
#pragma unroll
        for (int ni = 0; ni < 4; ++ni) C[ro + col0 + ni * 16] = f2bf(acc[mi][ni][r]);
      }
  } else {
    float* C = (float*)Cv + zh * sC1 + zl * sC2;
    const float* Rp = Res ? (Res + zh * sR1 + zl * sR2) : nullptr;
#pragma unroll
    for (int mi = 0; mi < 4; ++mi)
#pragma unroll
      for (int r = 0; r < 4; ++r) {
        int rw = row0 + mi * 16 + r;
#pragma unroll
        for (int ni = 0; ni < 4; ++ni) {
          float vv = acc[mi][ni][r];
          if constexpr (RES) vv += Rp[(size_t)rw * ldr + col0 + ni * 16];
          C[(size_t)rw * ldc + col0 + ni * 16] = vv;
        }
      }
  }
}

// ---------------------------------------------------------------- transpose-convert fp32[R][C] -> bf16[C][R]
__global__ __launch_bounds__(256) void k_transp(const float* __restrict__ in, size_t sI1, size_t sI2, int ldi,
                                                short* __restrict__ out, size_t sO1, size_t sO2, int ldo,
                                                int HB) {
  __shared__ float t[32][33];
  int z = blockIdx.z, zh = z / HB, zl = z - zh * HB;
  in += zh * sI1 + zl * sI2;
  out += zh * sO1 + zl * sO2;
  int r0 = blockIdx.x * 32, c0 = blockIdx.y * 32;
  int tx = threadIdx.x & 31, ty = threadIdx.x >> 5;
#pragma unroll
  for (int i = 0; i < 4; ++i) {
    int rr = ty + i * 8;
    t[rr][tx] = in[(size_t)(r0 + rr) * ldi + c0 + tx];
  }
  __syncthreads();
#pragma unroll
  for (int i = 0; i < 4; ++i) {
    int cr = ty + i * 8;
    out[(size_t)(c0 + cr) * ldo + r0 + tx] = f2bf(t[tx][cr]);
  }
}

// ---------------------------------------------------------------- causal depthwise conv(K=3)+silu (+bf16 out)
__global__ __launch_bounds__(256) void k_conv_silu(const float* __restrict__ in, int inLd, int logC,
                                                   const float* __restrict__ w,
                                                   const float* __restrict__ bias,
                                                   float* __restrict__ out,
                                                   short* __restrict__ out16) {
  int idx = blockIdx.x * 256 + threadIdx.x;
  int C = 1 << logC;
  int t = idx >> logC, c = idx & (C - 1);
  int s = t & 1023;
  const float* ip = in + (size_t)t * inLd + c;
  float acc = bias[c] + w[c * 3 + 2] * ip[0];
  if (s >= 1) acc += w[c * 3 + 1] * ip[-(ptrdiff_t)inLd];
  if (s >= 2) acc += w[c * 3 + 0] * ip[-2 * (ptrdiff_t)inLd];
  float r = acc / (1.f + __expf(-acc));
  out[(size_t)t * C + c] = r;
  if (out16) out16[(size_t)t * C + c] = f2bf(r);
}

// ---------------------------------------------------------------- FUSED: block-diag q,k,v + ig/fg projections
// One block per token t. q/k/v stay in registers; only v (fp32, for V^T), q16,k16 (bf16) hit memory.
// ig/fg reduce tail copied verbatim from the verified k_igfg.
__global__ __launch_bounds__(256) void k_qkvig(const float* __restrict__ xc, const float* __restrict__ x2,
                                               const float* __restrict__ Wq, const float* __restrict__ Wk,
                                               const float* __restrict__ Wv,
                                               const float* __restrict__ Wi, const float* __restrict__ bi,
                                               const float* __restrict__ Wf, const float* __restrict__ bf,
                                               float* __restrict__ v,
                                               short* __restrict__ q16, short* __restrict__ k16,
                                               float* __restrict__ ig, float* __restrict__ fg) {
  int t = blockIdx.x, n = threadIdx.x;
  const float4 xcv = *reinterpret_cast<const float4*>(xc + (size_t)t * 1024 + n * 4);
  const float4 xmv = *reinterpret_cast<const float4*>(x2 + (size_t)t * 2048 + n * 4);
  float qa[4], ka[4], va[4];
#pragma unroll
  for (int o = 0; o < 4; ++o) {
    const float4 wq = *reinterpret_cast<const float4*>(Wq + n * 16 + o * 4);
    const float4 wk = *reinterpret_cast<const float4*>(Wk + n * 16 + o * 4);
    const float4 wv = *reinterpret_cast<const float4*>(Wv + n * 16 + o * 4);
    qa[o] = xcv.x * wq.x + xcv.y * wq.y + xcv.z * wq.z + xcv.w * wq.w;
    ka[o] = xcv.x * wk.x + xcv.y * wk.y + xcv.z * wk.z + xcv.w * wk.w;
    va[o] = xmv.x * wv.x + xmv.y * wv.y + xmv.z * wv.z + xmv.w * wv.w;
  }
  *reinterpret_cast<float4*>(v + (size_t)t * 1024 + n * 4) = make_float4(va[0], va[1], va[2], va[3]);
  *reinterpret_cast<short4*>(q16 + (size_t)t * 1024 + n * 4) =
      make_short4(f2bf(qa[0]), f2bf(qa[1]), f2bf(qa[2]), f2bf(qa[3]));
  *reinterpret_cast<short4*>(k16 + (size_t)t * 1024 + n * 4) =
      make_short4(f2bf(ka[0]), f2bf(ka[1]), f2bf(ka[2]), f2bf(ka[3]));
  // ig/fg partials from registers: this thread owns channels c = 4n..4n+3
  float aI[4] = {0.f, 0.f, 0.f, 0.f}, aF[4] = {0.f, 0.f, 0.f, 0.f};
#pragma unroll
  for (int j = 0; j < 4; ++j) {
    int c = n * 4 + j;
    const float4 wiq = *reinterpret_cast<const float4*>(Wi + (size_t)c * 4);
    const float4 wik = *reinterpret_cast<const float4*>(Wi + (size_t)(1024 + c) * 4);
    const float4 wiv = *reinterpret_cast<const float4*>(Wi + (size_t)(2048 + c) * 4);
    const float4 wfq = *reinterpret_cast<const float4*>(Wf + (size_t)c * 4);
    const float4 wfk = *reinterpret_cast<const float4*>(Wf + (size_t)(1024 + c) * 4);
    const float4 wfv = *reinterpret_cast<const float4*>(Wf + (size_t)(2048 + c) * 4);
    aI[0] += qa[j] * wiq.x + ka[j] * wik.x + va[j] * wiv.x;
    aI[1] += qa[j] * wiq.y + ka[j] * wik.y + va[j] * wiv.y;
    aI[2] += qa[j] * wiq.z + ka[j] * wik.z + va[j] * wiv.z;
    aI[3] += qa[j] * wiq.w + ka[j] * wik.w + va[j] * wiv.w;
    aF[0] += qa[j] * wfq.x + ka[j] * wfk.x + va[j] * wfv.x;
    aF[1] += qa[j] * wfq.y + ka[j] * wfk.y + va[j] * wfv.y;
    aF[2] += qa[j] * wfq.z + ka[j] * wfk.z + va[j] * wfv.z;
    aF[3] += qa[j] * wfq.w + ka[j] * wfk.w + va[j] * wfv.w;
  }
#pragma unroll
  for (int h = 0; h < 4; ++h) { aI[h] = wsum(aI[h]); aF[h] = wsum(aF[h]); }
  __shared__ float red[2][4][4];
  int wv2 = n >> 6;
  if ((n & 63) == 0) {
#pragma unroll
    for (int h = 0; h < 4; ++h) { red[0][wv2][h] = aI[h]; red[1][wv2][h] = aF[h]; }
  }
  __syncthreads();
  if (n < 8) {
    int which = n >> 2, h = n & 3;
    float sum = red[which][0][h] + red[which][1][h] + red[which][2][h] + red[which][3][h];
    int b = t >> 10, s = t & 1023;
    size_t o = (size_t)(b * 4 + h) * 1024 + s;
    if (which == 0) ig[o] = sum + bi[h];
    else            fg[o] = sum + bf[h];
  }
}

// ---------------------------------------------------------------- per-(b,h) gate scans
__global__ __launch_bounds__(1024) void k_gatescan(const float* __restrict__ ig, const float* __restrict__ fg,
                                                   float* __restrict__ a, float* __restrict__ Mx,
                                                   float* __restrict__ emax) {
  int bh = blockIdx.x, s = threadIdx.x;
  size_t o = (size_t)bh * 1024 + s;
  float f = fg[o];
  float lf = (f >= 0.f) ? -log1pf(__expf(-f)) : (f - log1pf(__expf(f)));
  __shared__ float buf[1024];
  float val = lf;
  buf[s] = val;
  __syncthreads();
#pragma unroll
  for (int off = 1; off < 1024; off <<= 1) {
    float add = (s >= off) ? buf[s - off] : 0.f;
    __syncthreads();
    val += add; buf[s] = val;
    __syncthreads();
  }
  float csv = val;
  float av = ig[o] - csv;
  float mv = av;
  buf[s] = mv;
  __syncthreads();
#pragma unroll
  for (int off = 1; off < 1024; off <<= 1) {
    float other = (s >= off) ? buf[s - off] : -3.4e38f;
    __syncthreads();
    mv = fmaxf(mv, other); buf[s] = mv;
    __syncthreads();
  }
  a[o] = av;
  Mx[o] = mv;
  emax[o] = __expf(-(csv + mv));
}

// ---------------------------------------------------------------- mask+gate-weight+row-normalize (bf16, in place)
__global__ __launch_bounds__(256) void k_mask(short* __restrict__ P, const float* __restrict__ a,
                                              const float* __restrict__ Mx, const float* __restrict__ emax,
                                              int bhBase) {
  int i = blockIdx.x, z = blockIdx.y, tid = threadIdx.x;
  int bh = bhBase + z;
  short* Prow = P + ((size_t)z * 1024 + i) * 1024;
  const float* ab = a + (size_t)bh * 1024;
  float Mi = Mx[(size_t)bh * 1024 + i];
  float vals[4];
  float rs = 0.f;
#pragma unroll
  for (int jj = 0; jj < 4; ++jj) {
    int j = tid + jj * 256;
    float pv = 0.f;
    if (j <= i) pv = bf2f(Prow[j]) * 0.0625f * __expf(ab[j] - Mi);
    vals[jj] = pv;
    rs += pv;
  }
  rs = wsum(rs);
  __shared__ float red[4];
  if ((tid & 63) == 0) red[tid >> 6] = rs;
  __syncthreads();
  float tot = red[0] + red[1] + red[2] + red[3];
  float norm = fmaxf(fabsf(tot), emax[(size_t)bh * 1024 + i]) + 1e-6f;
  float inv = 1.f / norm;
#pragma unroll
  for (int jj = 0; jj < 4; ++jj) Prow[tid + jj * 256] = f2bf(vals[jj] * inv);
}

// ---------------------------------------------------------------- mLSTM headnorm + skip + silu(z) combine -> bf16
__global__ __launch_bounds__(256) void k_hncomb(const float* __restrict__ hattn, const float* __restrict__ xc,
                                                const float* __restrict__ x2, const float* __restrict__ onorm,
                                                const float* __restrict__ skip, short* __restrict__ out) {
  int t = blockIdx.x, tid = threadIdx.x;
  int w = tid >> 6, lane = tid & 63;
  int cbase = w * 256 + lane * 4;
  const float4 v = *reinterpret_cast<const float4*>(hattn + (size_t)t * 1024 + cbase);
  float s = v.x + v.y + v.z + v.w;
  float s2 = v.x * v.x + v.y * v.y + v.z * v.z + v.w * v.w;
  s = wsum(s); s2 = wsum(s2);
  float mu = s * (1.f / 256.f), var = s2 * (1.f / 256.f) - mu * mu;
  float r = rsqrtf(var + EPSV);
  const float4 on4 = *reinterpret_cast<const float4*>(onorm + cbase);
  const float4 sk4 = *reinterpret_cast<const float4*>(skip + cbase);
  const float4 xc4 = *reinterpret_cast<const float4*>(xc + (size_t)t * 1024 + cbase);
  const float4 z4 = *reinterpret_cast<const float4*>(x2 + (size_t)t * 2048 + 1024 + cbase);
  float4 o;
  o.x = ((v.x - mu) * r * on4.x + sk4.x * xc4.x) * (z4.x / (1.f + __expf(-z4.x)));
  o.y = ((v.y - mu) * r * on4.y + sk4.y * xc4.y) * (z4.y / (1.f + __expf(-z4.y)));
  o.z = ((v.z - mu) * r * on4.z + sk4.z * xc4.z) * (z4.z / (1.f + __expf(-z4.z)));
  o.w = ((v.w - mu) * r * on4.w + sk4.w * xc4.w) * (z4.w / (1.f + __expf(-z4.w)));
  *reinterpret_cast<short4*>(out + (size_t)t * 1024 + cbase) =
      make_short4(f2bf(o.x), f2bf(o.y), f2bf(o.z), f2bf(o.w));
}

// ---------------------------------------------------------------- concat+convert sLSTM gate weights -> bf16
__global__ __launch_bounds__(256) void k_wcat(const float* __restrict__ wi, const float* __restrict__ wf,
                                              const float* __restrict__ wz, const float* __restrict__ wo,
                                              short* __restrict__ Wcat) {
  int idx = blockIdx.x * 256 + threadIdx.x;
  int g = idx >> 16, r = idx & 65535;
  const float* s = (g == 0) ? wi : ((g == 1) ? wf : ((g == 2) ? wz : wo));
  Wcat[idx] = f2bf(s[r]);
}

// ---------------------------------------------------------------- sLSTM sequential scan, one block per (b,h)
// 512 threads = (e, q): thread computes 32-deep partial dots (d in [32q,32q+32))
// for ALL 4 gates of element e; 2-step quad butterfly completes all 4 raws on
// every thread. R partials pinned in VGPRs via asm (128 f32/thread).
__global__ __launch_bounds__(512, 1) void k_scan(const float* __restrict__ Wx, const float* __restrict__ R,
                                                 const float* __restrict__ bias, float* __restrict__ ys) {
  int bh = blockIdx.x, b = bh >> 2, h = bh & 3;
  int tid = threadIdx.x;
  int e = tid >> 2, q = tid & 3;
  // rcg[g][i] = { R[h][32q+2i][g*128+e], R[h][32q+2i+1][g*128+e] }
  f32x2 rc0[16], rc1[16], rc2[16], rc3[16];
  {
    const float* Rp = R + (size_t)h * 65536 + (size_t)(q * 32) * 512 + e;
#pragma unroll
    for (int i = 0; i < 16; ++i) {
      const float* p0 = Rp + (size_t)(2 * i) * 512;
      const float* p1 = Rp + (size_t)(2 * i + 1) * 512;
      rc0[i][0] = p0[0];   rc0[i][1] = p1[0];
      rc1[i][0] = p0[128]; rc1[i][1] = p1[128];
      rc2[i][0] = p0[256]; rc2[i][1] = p1[256];
      rc3[i][0] = p0[384]; rc3[i][1] = p1[384];
    }
  }
  // pin R fragments in VGPRs — forbid remat/sinking into the loop
#pragma unroll
  for (int i = 0; i < 16; ++i)
    asm volatile("" : "+v"(rc0[i]), "+v"(rc1[i]), "+v"(rc2[i]), "+v"(rc3[i]));

  const float addb = bias[(size_t)q * 512 + h * 128 + e];  // bias for gate q, elem e
  const float* wxp = Wx + (size_t)b * 1024 * 2048 + h * 512 + q * 128 + e;  // gate q's wx
  __shared__ float ysh[2][128];
  if (tid < 128) { ysh[0][tid] = 0.f; ysh[1][tid] = 0.f; }
  float c_ = 0.f, n_ = 0.f, m_ = 0.f;
  float wx = wxp[0];
  float* ysg = ys + ((size_t)b * 1024) * 512 + h * 128 + e;
  __syncthreads();
  for (int s = 0; s < 1024; ++s) {
    const float* yq = &ysh[(s + 1) & 1][q * 32];   // this thread's d-quarter of y_{s-1}
    int sp = (s + 1 < 1024) ? (s + 1) : 1023;
    float wxn = wxp[(size_t)sp * 2048];            // prefetch next wx
    f32x2 p0 = {0.f, 0.f}, p1 = {0.f, 0.f}, p2 = {0.f, 0.f}, p3 = {0.f, 0.f};
#pragma unroll
    for (int i = 0; i < 8; ++i) {
      const f32x4 y4 = *reinterpret_cast<const f32x4*>(yq + i * 4);
      const f32x2 yA = {y4[0], y4[1]};
      const f32x2 yB = {y4[2], y4[3]};
      p0 = yA * rc0[2 * i] + p0;  p0 = yB * rc0[2 * i + 1] + p0;
      p1 = yA * rc1[2 * i] + p1;  p1 = yB * rc1[2 * i + 1] + p1;
      p2 = yA * rc2[2 * i] + p2;  p2 = yB * rc2[2 * i + 1] + p2;
      p3 = yA * rc3[2 * i] + p3;  p3 = yB * rc3[2 * i + 1] + p3;
    }
    float pr0 = p0[0] + p0[1];
    float pr1 = p1[0] + p1[1];
    float pr2 = p2[0] + p2[1];
    float pr3 = p3[0] + p3[1];
    // fold wx+bias on the diagonal (thread q owns gate q's wx)
    float add = wx + addb;
    pr0 += (q == 0) ? add : 0.f;
    pr1 += (q == 1) ? add : 0.f;
    pr2 += (q == 2) ? add : 0.f;
    pr3 += (q == 3) ? add : 0.f;
    // quad butterfly: every thread ends with all 4 complete raws
    pr0 += __shfl_xor(pr0, 1, 64); pr1 += __shfl_xor(pr1, 1, 64);
    pr2 += __shfl_xor(pr2, 1, 64); pr3 += __shfl_xor(pr3, 1, 64);
    pr0 += __shfl_xor(pr0, 2, 64); pr1 += __shfl_xor(pr1, 2, 64);
    pr2 += __shfl_xor(pr2, 2, 64); pr3 += __shfl_xor(pr3, 2, 64);
    float ir = pr0, fr = pr1, zr = pr2, orr = pr3;
    // gate chain (redundant per quad)
    float lsf = (fr >= 0.f) ? -__logf(1.f + __expf(-fr)) : (fr - __logf(1.f + __expf(fr)));
    float lfm = m_ + lsf;
    float mn = fmaxf(ir, lfm);
    float igt = __expf(ir - mn);
    float fgt = __expf(lfm - mn);
    float t2 = __expf(-2.f * fabsf(zr));
    float th = (1.f - t2) / (1.f + t2);
    th = (zr >= 0.f) ? th : -th;
    float cn = fgt * c_ + igt * th;
    float nn = fgt * n_ + igt;
    float yn = cn / (nn * (1.f + __expf(-orr)));
    c_ = cn; n_ = nn; m_ = mn;
    if (q == 0) {
      ysh[s & 1][e] = yn;
      ysg[(size_t)s * 512] = yn;
    }
    wx = wxn;
    __syncthreads();
  }
}

// ---------------------------------------------------------------- sLSTM headnorm(128)+gn + residual
__global__ __launch_bounds__(512) void k_hnadd(const float* __restrict__ hin, const float* __restrict__ ysv,
                                               const float* __restrict__ gn, float* __restrict__ out) {
  int t = blockIdx.x, tid = threadIdx.x;
  float yv = ysv[(size_t)t * 512 + tid];
  float s = wsum(yv), s2 = wsum(yv * yv);
  __shared__ float l1[8], l2[8];
  int wv = tid >> 6;
  if ((tid & 63) == 0) { l1[wv] = s; l2[wv] = s2; }
  __syncthreads();
  int h2 = (tid >> 7) * 2;
  float S = l1[h2] + l1[h2 + 1], S2 = l2[h2] + l2[h2 + 1];
  float mu = S * (1.f / 128.f), var = S2 * (1.f / 128.f) - mu * mu;
  float r = rsqrtf(var + EPSV);
  out[(size_t)t * 512 + tid] = hin[(size_t)t * 512 + tid] + (yv - mu) * r * gn[tid];
}

// ---------------------------------------------------------------- gelu(g)*up -> bf16
__global__ __launch_bounds__(256) void k_geluprod(const float* __restrict__ u, short* __restrict__ gp) {
  int idx = blockIdx.x * 256 + threadIdx.x;
  int t = idx >> 9, c = idx & 511;
  float g = u[(size_t)t * 1024 + c];
  float up = u[(size_t)t * 1024 + 512 + c];
  float ge = 0.5f * g * (1.f + erff(g * 0.70710678118654752f));
  gp[idx] = f2bf(ge * up);
}

// ---------------------------------------------------------------- final LN(last token) + classifier
__global__ __launch_bounds__(128) void k_final(const float* __restrict__ h, const float* __restrict__ w,
                                               const float* __restrict__ cw, const float* __restrict__ cb,
                                               float* __restrict__ out) {
  int b = blockIdx.x, tid = threadIdx.x;
  const float* row = h + ((size_t)(b * 1024 + 1023)) * 512;
  const float4 v = *reinterpret_cast<const float4*>(row + tid * 4);
  float s = v.x + v.y + v.z + v.w;
  float s2 = v.x * v.x + v.y * v.y + v.z * v.z + v.w * v.w;
  s = wsum(s); s2 = wsum(s2);
  __shared__ float l1[2], l2[2];
  int wv = tid >> 6;
  if ((tid & 63) == 0) { l1[wv] = s; l2[wv] = s2; }
  __syncthreads();
  s = l1[0] + l1[1]; s2 = l2[0] + l2[1];
  float mu = s * (1.f / 512.f);
  float var = s2 * (1.f / 512.f) - mu * mu;
  float r = rsqrtf(var + EPSV);
  const float4 w4 = *reinterpret_cast<const float4*>(w + tid * 4);
  const float4 c4 = *reinterpret_cast<const float4*>(cw + tid * 4);
  float d = (v.x - mu) * r * w4.x * c4.x + (v.y - mu) * r * w4.y * c4.y +
            (v.z - mu) * r * w4.z * c4.z + (v.w - mu) * r * w4.w * c4.w;
  d = wsum(d);
  __syncthreads();
  if ((tid & 63) == 0) l1[tid >> 6] = d;
  __syncthreads();
  if (tid == 0) out[b] = l1[0] + l1[1] + cb[0];
}

// ================================================================ host
extern "C" void kernel_launch(void* const* d_in, const int* in_sizes, int n_in,
                              void* d_out, int out_size, void* d_ws, size_t ws_size,
                              hipStream_t stream) {
  (void)in_sizes; (void)n_in; (void)out_size; (void)ws_size;
  auto F = [&](int i) { return (const float*)d_in[i]; };
  const int* x = (const int*)d_in[0];
  const float* emb = F(1);

  float* ws = (float*)d_ws;
  size_t off = 0;
  auto alloc = [&](size_t n) { float* p = ws + off; off += n; return p; };
  float* hA = alloc(2097152);
  float* hB = alloc(2097152);
  float* X2 = alloc(8388608);
  float* C1 = alloc(4194304);
  float* C2 = alloc(4194304);
  float* C3 = alloc(4194304);
  float* C4 = alloc(4194304);
  float* C5 = alloc(4194304);
  float* g_a = alloc(16384);
  float* g_M = alloc(16384);
  float* g_e = alloc(16384);
  float* g_ig = alloc(16384);
  float* g_fg = alloc(16384);
  short* q16 = (short*)alloc(2097152);   // 4096x1024 bf16
  short* k16 = (short*)alloc(2097152);
  short* A16a = (short*)alloc(1048576);  // 4096x512 bf16
  short* A16b = (short*)alloc(1048576);
  short* WT = (short*)alloc(524288);     // up to 2048x512 bf16
  short* Wc16 = (short*)alloc(131072);
  short* Pb16 = (short*)C2;              // 8x1024x1024 bf16 scores (C2 dead then)
  short* VT = (short*)C3;                // 16x256x1024 bf16 V^T (C3 dead then)
  short* H16 = (short*)q16;              // 4096x1024 bf16 (q16 dead then)

  k_embed<<<4096, 128, 0, stream>>>(x, emb, hA);

  auto mlstm = [&](int pi, const float* hin, float* hout) {
    const float* ln = F(pi);       const float* Wup = F(pi + 1);
    const float* convW = F(pi + 2); const float* convb = F(pi + 3);
    const float* Wq = F(pi + 4);   const float* Wk = F(pi + 5);  const float* Wv = F(pi + 6);
    const float* Wi = F(pi + 7);   const float* bi = F(pi + 8);
    const float* Wf = F(pi + 9);   const float* bf_ = F(pi + 10);
    const float* skip = F(pi + 11); const float* onorm = F(pi + 12);
    const float* Wdown = F(pi + 13);

    k_ln512<<<4096, 128, 0, stream>>>(hin, ln, nullptr, A16a);
    k_transp<<<dim3(16, 64, 1), 256, 0, stream>>>(Wup, 0, 0, 2048, WT, 0, 0, 512, 1);
    k_mm<false, false><<<dim3(16, 32, 1), 256, 0, stream>>>(
        A16a, 0, 0, 512, WT, 0, 0, 512, nullptr, 0, 0, 0, X2, 0, 0, 2048, 512, 1);
    k_conv_silu<<<(4096 * 1024) / 256, 256, 0, stream>>>(X2, 2048, 10, convW, convb, C1, nullptr);
    k_qkvig<<<4096, 256, 0, stream>>>(C1, X2, Wq, Wk, Wv, Wi, bi, Wf, bf_, C4, q16, k16, g_ig, g_fg);
    k_gatescan<<<16, 1024, 0, stream>>>(g_ig, g_fg, g_a, g_M, g_e);
    // V^T (per bh: [1024s][256d] stride 1024 -> [256][1024] bf16)
    k_transp<<<dim3(32, 8, 16), 256, 0, stream>>>(C4, 1048576, 256, 1024, VT, 1048576, 262144, 1024, 4);
    for (int c = 0; c < 2; ++c) {
      const short* qc = q16 + (size_t)c * 2097152;
      const short* kc = k16 + (size_t)c * 2097152;
      k_mm<true, false><<<dim3(8, 8, 8), 256, 0, stream>>>(
          qc, 1048576, 256, 1024, kc, 1048576, 256, 1024,
          nullptr, 0, 0, 0, Pb16, 4194304, 1048576, 1024, 256, 4);
      k_mask<<<dim3(1024, 8), 256, 0, stream>>>(Pb16, g_a, g_M, g_e, c * 8);
      k_mm<false, false><<<dim3(2, 8, 8), 256, 0, stream>>>(
          Pb16, 4194304, 1048576, 1024, VT + (size_t)c * 8 * 262144, 1048576, 262144, 1024,
          nullptr, 0, 0, 0, C5 + (size_t)c * 2097152, 1048576, 256, 1024, 1024, 4);
    }
    k_hncomb<<<4096, 256, 0, stream>>>(C5, C1, X2, onorm, skip, H16);
    k_transp<<<dim3(32, 16, 1), 256, 0, stream>>>(Wdown, 0, 0, 512, WT, 0, 0, 1024, 1);
    k_mm<false, true><<<dim3(4, 32, 1), 256, 0, stream>>>(
        H16, 0, 0, 1024, WT, 0, 0, 1024, hin, 0, 0, 512, hout, 0, 0, 512, 1024, 1);
  };

  auto slstm = [&](const float* hin, float* hout) {
    const float* ln1 = F(30); const float* convW = F(31); const float* convb = F(32);
    const float* Wig = F(33); const float* Wfg = F(34); const float* Wzg = F(35);
    const float* Wog = F(36); const float* Rr = F(37);  const float* bias = F(38);
    const float* gn = F(39);  const float* ln2 = F(40);
    const float* Wu = F(41);  const float* Wd = F(42);

    k_ln512<<<4096, 128, 0, stream>>>(hin, ln1, C3, A16a);                          // xn
    k_conv_silu<<<(4096 * 512) / 256, 256, 0, stream>>>(C3, 512, 9, convW, convb, C4, A16b);  // xc
    k_wcat<<<(4 * 65536) / 256, 256, 0, stream>>>(Wig, Wfg, Wzg, Wog, Wc16);
    k_mm<false, false><<<dim3(1, 32, 8), 256, 0, stream>>>(                          // i,f from xc
        A16b, 128, 0, 512, Wc16, 16384, 65536, 128,
        nullptr, 0, 0, 0, X2, 512, 128, 2048, 128, 2);
    k_mm<false, false><<<dim3(1, 32, 8), 256, 0, stream>>>(                          // z,o from xn
        A16a, 128, 0, 512, Wc16 + 131072, 16384, 65536, 128,
        nullptr, 0, 0, 0, X2 + 256, 512, 128, 2048, 128, 2);
    k_scan<<<16, 512, 0, stream>>>(X2, Rr, bias, C2);
    k_hnadd<<<4096, 512, 0, stream>>>(hin, C2, gn, C3);
    k_ln512<<<4096, 128, 0, stream>>>(C3, ln2, nullptr, A16a);
    k_transp<<<dim3(16, 32, 1), 256, 0, stream>>>(Wu, 0, 0, 1024, WT, 0, 0, 512, 1);
    k_mm<false, false><<<dim3(8, 32, 1), 256, 0, stream>>>(
        A16a, 0, 0, 512, WT, 0, 0, 512, nullptr, 0, 0, 0, C5, 0, 0, 1024, 512, 1);
    k_geluprod<<<(4096 * 512) / 256, 256, 0, stream>>>(C5, A16b);
    k_transp<<<dim3(16, 16, 1), 256, 0, stream>>>(Wd, 0, 0, 512, WT, 0, 0, 512, 1);
    k_mm<false, true><<<dim3(4, 32, 1), 256, 0, stream>>>(
        A16b, 0, 0, 512, WT, 0, 0, 512, C3, 0, 0, 512, hout, 0, 0, 512, 512, 1);
  };

  mlstm(2, hA, hB);
  slstm(hB, hA);
  mlstm(16, hA, hB);
  k_final<<<4, 128, 0, stream>>>(hB, F(43), F(44), F(45), (float*)d_out);
}